// Round 2
// baseline (636.071 us; speedup 1.0000x reference)
//
#include <hip/hip_runtime.h>
#include <math.h>

#define NN 40000
#define EE 500000
#define CC 128
#define GG 800
#define FINN 56
#define NEGS 0.2f

__device__ __forceinline__ float lrelu(float x) { return x > 0.f ? x : NEGS * x; }

// ---------------- CSR build ----------------
__global__ void k_hist(const int* __restrict__ dst, int* __restrict__ deg) {
    int e = blockIdx.x * 256 + threadIdx.x;
    if (e < EE) atomicAdd(&deg[dst[e]], 1);
}

__global__ void k_scanA(const int* __restrict__ deg, int* __restrict__ row1, int* __restrict__ bsum) {
    __shared__ int buf[256];
    int i = blockIdx.x * 256 + threadIdx.x;
    int v = (i < NN) ? deg[i] : 0;
    buf[threadIdx.x] = v;
    __syncthreads();
    for (int off = 1; off < 256; off <<= 1) {
        int t = (threadIdx.x >= off) ? buf[threadIdx.x - off] : 0;
        __syncthreads();
        buf[threadIdx.x] += t;
        __syncthreads();
    }
    if (i < NN) row1[i] = buf[threadIdx.x];
    if (threadIdx.x == 255) bsum[blockIdx.x] = buf[255];
}

__global__ void k_scanB(int* bsum, int nb) {
    __shared__ int buf[256];
    int v = (threadIdx.x < nb) ? bsum[threadIdx.x] : 0;
    buf[threadIdx.x] = v;
    __syncthreads();
    for (int off = 1; off < 256; off <<= 1) {
        int t = (threadIdx.x >= off) ? buf[threadIdx.x - off] : 0;
        __syncthreads();
        buf[threadIdx.x] += t;
        __syncthreads();
    }
    if (threadIdx.x < nb) bsum[threadIdx.x] = buf[threadIdx.x] - v;  // exclusive
}

__global__ void k_scanC(int* __restrict__ row_ptr, const int* __restrict__ bsum) {
    int i = blockIdx.x * 256 + threadIdx.x;
    if (i < NN) row_ptr[i + 1] += bsum[blockIdx.x];
    if (i == 0) row_ptr[0] = 0;
}

__global__ void k_copycur(const int* __restrict__ row_ptr, int* __restrict__ cursor) {
    int i = blockIdx.x * 256 + threadIdx.x;
    if (i < NN) cursor[i] = row_ptr[i];
}

__global__ void k_scatter(const int* __restrict__ ei, const float* __restrict__ ea,
                          const float* __restrict__ mu, const float* __restrict__ dev,
                          int* __restrict__ cursor, int* __restrict__ csr_src,
                          float* __restrict__ csr_a1, float* __restrict__ csr_a2) {
    int e = blockIdx.x * 256 + threadIdx.x;
    if (e >= EE) return;
    int s = ei[e], d = ei[EE + e];
    float a1 = ea[2 * e];
    float xx = ea[2 * e + 1] - mu[0];
    float a2 = expf(-xx * xx / dev[0]) + a1;
    int p = atomicAdd(&cursor[d], 1);
    csr_src[p] = s;
    csr_a1[p] = a1;
    csr_a2[p] = a2;
}

// we_dot[k*2+h] = sum_c We[k,0,h*128+c] * att_e[k,h,c]
__global__ void k_wedot(const float* __restrict__ We, const float* __restrict__ ate, float* __restrict__ wd) {
    int lane = threadIdx.x;  // 64
    for (int idx = 0; idx < 6; ++idx) {
        const float* w = We + idx * 128;   // flat: k*256 + h*128
        const float* a = ate + idx * 128;
        float p = w[lane] * a[lane] + w[lane + 64] * a[lane + 64];
        #pragma unroll
        for (int m = 32; m; m >>= 1) p += __shfl_xor(p, m);
        if (lane == 0) wd[idx] = p;
    }
}

// ---------------- embed: h = x @ W_emb  (N,56)@(56,128) ----------------
__global__ __launch_bounds__(128) void k_embed(const float* __restrict__ x, const float* __restrict__ W,
                                               float* __restrict__ h) {
    __shared__ float xs[FINN];
    int n = blockIdx.x, t = threadIdx.x;
    if (t < FINN) xs[t] = x[n * FINN + t];
    __syncthreads();
    float acc = 0.f;
    #pragma unroll
    for (int f = 0; f < FINN; ++f) acc += xs[f] * W[f * CC + t];
    h[n * CC + t] = acc;
}

// ---------------- hh = h @ Wg[k]  (N,128)@(128,256) ----------------
__global__ __launch_bounds__(256) void k_gemm(const float* __restrict__ A, const float* __restrict__ W,
                                              float* __restrict__ Bout) {
    __shared__ float aT[32][36];    // [k][row], padded
    __shared__ float wT[32][256];   // [k][col]
    float acc[8][4] = {};
    int tid = threadIdx.x;
    int cg = tid & 63;   // col group (4 cols)
    int rg = tid >> 6;   // row group (8 rows)
    int row0 = blockIdx.x * 32;
    for (int kc = 0; kc < 4; ++kc) {
        {
            int r = tid >> 3, c0 = (tid & 7) * 4;
            float4 v = *(const float4*)&A[(row0 + r) * CC + kc * 32 + c0];
            aT[c0 + 0][r] = v.x; aT[c0 + 1][r] = v.y; aT[c0 + 2][r] = v.z; aT[c0 + 3][r] = v.w;
        }
        #pragma unroll
        for (int i = 0; i < 8; ++i) {
            int flat = i * 1024 + tid * 4;
            int wr = flat >> 8, wc = flat & 255;
            *(float4*)&wT[wr][wc] = *(const float4*)&W[(kc * 32 + wr) * 256 + wc];
        }
        __syncthreads();
        #pragma unroll
        for (int kk = 0; kk < 32; ++kk) {
            float a0[8];
            #pragma unroll
            for (int i = 0; i < 8; ++i) a0[i] = aT[kk][rg * 8 + i];
            float4 w4 = *(const float4*)&wT[kk][cg * 4];
            #pragma unroll
            for (int i = 0; i < 8; ++i) {
                acc[i][0] += a0[i] * w4.x; acc[i][1] += a0[i] * w4.y;
                acc[i][2] += a0[i] * w4.z; acc[i][3] += a0[i] * w4.w;
            }
        }
        __syncthreads();
    }
    #pragma unroll
    for (int i = 0; i < 8; ++i) {
        float4 o = make_float4(acc[i][0], acc[i][1], acc[i][2], acc[i][3]);
        *(float4*)&Bout[(size_t)(row0 + rg * 8 + i) * 256 + cg * 4] = o;
    }
}

// ---------------- ls/ld: per (n,h) dot of hh row with att vectors ----------------
__global__ __launch_bounds__(256) void k_lsld(const float* __restrict__ hh, const float* __restrict__ as_,
                                              const float* __restrict__ ad_, float* __restrict__ ls,
                                              float* __restrict__ ld) {
    int wid = threadIdx.x >> 6, lane = threadIdx.x & 63;
    int idx = blockIdx.x * 4 + wid;  // (n,h)
    if (idx >= NN * 2) return;
    int n = idx >> 1, h = idx & 1;
    const float* base = hh + (size_t)n * 256 + h * 128;
    const float* a1 = as_ + h * 128;
    const float* a2 = ad_ + h * 128;
    float v0 = base[lane], v1 = base[lane + 64];
    float ps = v0 * a1[lane] + v1 * a1[lane + 64];
    float pd = v0 * a2[lane] + v1 * a2[lane + 64];
    #pragma unroll
    for (int m = 32; m; m >>= 1) { ps += __shfl_xor(ps, m); pd += __shfl_xor(pd, m); }
    if (lane == 0) { ls[idx] = ps; ld[idx] = pd; }
}

// ---------------- fused attention (both gates) + epilogue ----------------
__global__ __launch_bounds__(256) void k_attn(
    const float* __restrict__ hh, const float* __restrict__ hcur,
    const float* __restrict__ ls, const float* __restrict__ ld,
    const int* __restrict__ row_ptr, const int* __restrict__ csr_src,
    const float* __restrict__ csr_a1, const float* __restrict__ csr_a2,
    const float* __restrict__ wd, const float* __restrict__ bg,
    const float* __restrict__ gw, const float* __restrict__ gb,
    float* __restrict__ hout) {
    int wid = threadIdx.x >> 6, lane = threadIdx.x & 63;
    int n = blockIdx.x * 4 + wid;
    if (n >= NN) return;
    float wd0 = wd[0], wd1 = wd[1];
    float ld0 = ld[n * 2 + 0], ld1 = ld[n * 2 + 1];
    int start = row_ptr[n], end = row_ptr[n + 1];

    // pass A: global max of leaky logits per (head, gate)
    float mx0 = -INFINITY, mx1 = -INFINITY, mx2 = -INFINITY, mx3 = -INFINITY;
    for (int j0 = start; j0 < end; j0 += 64) {
        int j = j0 + lane;
        if (j < end) {
            int s = csr_src[j];
            float ls0 = ls[s * 2], ls1 = ls[s * 2 + 1];
            float a1 = csr_a1[j], a2 = csr_a2[j];
            float b0 = ls0 + ld0, b1 = ls1 + ld1;
            mx0 = fmaxf(mx0, lrelu(b0 + a1 * wd0));
            mx1 = fmaxf(mx1, lrelu(b0 + a2 * wd0));
            mx2 = fmaxf(mx2, lrelu(b1 + a1 * wd1));
            mx3 = fmaxf(mx3, lrelu(b1 + a2 * wd1));
        }
    }
    #pragma unroll
    for (int m = 32; m; m >>= 1) {
        mx0 = fmaxf(mx0, __shfl_xor(mx0, m)); mx1 = fmaxf(mx1, __shfl_xor(mx1, m));
        mx2 = fmaxf(mx2, __shfl_xor(mx2, m)); mx3 = fmaxf(mx3, __shfl_xor(mx3, m));
    }

    int hd = lane >> 5;             // head owned for accumulation
    int cbase = (lane & 31) * 4;    // 4 channels owned
    float s0 = 0, s1 = 0, s2 = 0, s3 = 0;
    float acc1[4] = {0, 0, 0, 0}, acc2[4] = {0, 0, 0, 0};
    for (int j0 = start; j0 < end; j0 += 64) {
        int j = j0 + lane;
        int nact = min(64, end - j0);
        float e00 = 0, e01 = 0, e10 = 0, e11 = 0;
        int smine = 0;
        if (j < end) {
            smine = csr_src[j];
            float ls0 = ls[smine * 2], ls1 = ls[smine * 2 + 1];
            float a1 = csr_a1[j], a2 = csr_a2[j];
            float b0 = ls0 + ld0, b1 = ls1 + ld1;
            e00 = expf(lrelu(b0 + a1 * wd0) - mx0);
            e01 = expf(lrelu(b0 + a2 * wd0) - mx1);
            e10 = expf(lrelu(b1 + a1 * wd1) - mx2);
            e11 = expf(lrelu(b1 + a2 * wd1) - mx3);
            s0 += e00; s1 += e01; s2 += e10; s3 += e11;
        }
        for (int jj = 0; jj < nact; ++jj) {
            int s = __shfl(smine, jj);
            float f00 = __shfl(e00, jj), f01 = __shfl(e01, jj);
            float f10 = __shfl(e10, jj), f11 = __shfl(e11, jj);
            const float4 v = *(const float4*)&hh[(size_t)s * 256 + hd * 128 + cbase];
            float eg1 = hd ? f10 : f00;
            float eg2 = hd ? f11 : f01;
            acc1[0] += eg1 * v.x; acc1[1] += eg1 * v.y; acc1[2] += eg1 * v.z; acc1[3] += eg1 * v.w;
            acc2[0] += eg2 * v.x; acc2[1] += eg2 * v.y; acc2[2] += eg2 * v.z; acc2[3] += eg2 * v.w;
        }
    }
    #pragma unroll
    for (int m = 32; m; m >>= 1) {
        s0 += __shfl_xor(s0, m); s1 += __shfl_xor(s1, m);
        s2 += __shfl_xor(s2, m); s3 += __shfl_xor(s3, m);
    }

    float d1 = (hd ? s2 : s0) + 1e-16f;
    float d2 = (hd ? s3 : s1) + 1e-16f;
    float o1[4], o2[4];
    #pragma unroll
    for (int i = 0; i < 4; ++i) { o1[i] = acc1[i] / d1; o2[i] = acc2[i] / d2; }
    // mean over heads (partner lane l^32 holds the other head, same channels), + bg
    #pragma unroll
    for (int i = 0; i < 4; ++i) {
        o1[i] = 0.5f * (o1[i] + __shfl_xor(o1[i], 32)) + bg[cbase + i];
        o2[i] = 0.5f * (o2[i] + __shfl_xor(o2[i], 32)) + bg[cbase + i];
    }
    float4 h4 = *(const float4*)&hcur[(size_t)n * CC + cbase];
    float p1 = 0, p2 = 0;
    if (hd == 0) {
        #pragma unroll
        for (int i = 0; i < 4; ++i) {
            p1 += o1[i] * gw[128 + cbase + i];
            p2 += o2[i] * gw[128 + cbase + i];
        }
    } else {
        float hp = h4.x * gw[cbase] + h4.y * gw[cbase + 1] + h4.z * gw[cbase + 2] + h4.w * gw[cbase + 3];
        p1 = hp; p2 = hp;
    }
    #pragma unroll
    for (int m = 32; m; m >>= 1) { p1 += __shfl_xor(p1, m); p2 += __shfl_xor(p2, m); }
    float z1 = 1.f / (1.f + expf(-(p1 + gb[0])));
    float z2 = 1.f / (1.f + expf(-(p2 + gb[0])));
    if (hd == 0) {
        float hv[4] = {h4.x, h4.y, h4.z, h4.w};
        float r[4];
        #pragma unroll
        for (int i = 0; i < 4; ++i) {
            float g1 = z1 * hv[i] + (1.f - z1) * fmaxf(o1[i], 0.f);
            float g2 = z2 * hv[i] + (1.f - z2) * fmaxf(o2[i], 0.f);
            r[i] = g2 - g1;
        }
        *(float4*)&hout[(size_t)n * CC + cbase] = make_float4(r[0], r[1], r[2], r[3]);
    }
}

// ---------------- readout: segment sums over sorted batch_idx ----------------
__global__ __launch_bounds__(128) void k_readout(const float* __restrict__ h, const float* __restrict__ valid,
                                                 const int* __restrict__ batch, float* __restrict__ obuf) {
    int g = blockIdx.x, t = threadIdx.x;
    int lo = 0, hi = NN;
    while (lo < hi) { int mid = (lo + hi) >> 1; if (batch[mid] < g) lo = mid + 1; else hi = mid; }
    int s = lo;
    lo = s; hi = NN;
    while (lo < hi) { int mid = (lo + hi) >> 1; if (batch[mid] < g + 1) lo = mid + 1; else hi = mid; }
    int e = lo;
    float gl = 0, gp = 0;
    for (int n = s; n < e; ++n) {
        float hv = h[(size_t)n * CC + t];
        gl += hv * valid[n * 2];
        gp += hv * valid[n * 2 + 1];
    }
    obuf[g * 256 + t] = gl;
    obuf[g * 256 + 128 + t] = gp;
}

// ---------------- per-graph MLP ----------------
__global__ __launch_bounds__(128) void k_mlp(const float* __restrict__ obuf,
    const float* __restrict__ w0, const float* __restrict__ b0,
    const float* __restrict__ w1, const float* __restrict__ b1,
    const float* __restrict__ w2, const float* __restrict__ b2,
    const float* __restrict__ w3, const float* __restrict__ b3,
    float* __restrict__ out) {
    __shared__ float cur[256];
    __shared__ float nxt[128];
    int g = blockIdx.x, t = threadIdx.x;
    cur[t] = obuf[g * 256 + t];
    cur[t + 128] = obuf[g * 256 + 128 + t];
    __syncthreads();
    float s = b0[t];
    for (int i = 0; i < 256; ++i) s += cur[i] * w0[i * 128 + t];
    nxt[t] = fmaxf(s, 0.f);
    __syncthreads();
    s = b1[t];
    for (int i = 0; i < 128; ++i) s += nxt[i] * w1[i * 128 + t];
    cur[t] = fmaxf(s, 0.f);
    __syncthreads();
    s = b2[t];
    for (int i = 0; i < 128; ++i) s += cur[i] * w2[i * 128 + t];
    nxt[t] = fmaxf(s, 0.f);
    __syncthreads();
    if (t < 2) {
        float o = b3[t];
        for (int i = 0; i < 128; ++i) o += nxt[i] * w3[i * 2 + t];
        out[g * 2 + t] = (t == 1) ? expf(o) : o;
    }
}

extern "C" void kernel_launch(void* const* d_in, const int* in_sizes, int n_in,
                              void* d_out, int out_size, void* d_ws, size_t ws_size,
                              hipStream_t stream) {
    const float* x      = (const float*)d_in[0];
    const int*   ei     = (const int*)d_in[1];
    const float* ea     = (const float*)d_in[2];
    const float* valid  = (const float*)d_in[3];
    const int*   batch  = (const int*)d_in[4];
    const float* mu     = (const float*)d_in[5];
    const float* devp   = (const float*)d_in[6];
    const float* W_emb  = (const float*)d_in[7];
    const float* Wg     = (const float*)d_in[8];
    const float* att_s  = (const float*)d_in[9];
    const float* att_d  = (const float*)d_in[10];
    const float* We     = (const float*)d_in[11];
    const float* att_e  = (const float*)d_in[12];
    const float* bg     = (const float*)d_in[13];
    const float* gw     = (const float*)d_in[14];
    const float* gb     = (const float*)d_in[15];
    const float* fw0    = (const float*)d_in[16];
    const float* fb0    = (const float*)d_in[17];
    const float* fw1    = (const float*)d_in[18];
    const float* fb1    = (const float*)d_in[19];
    const float* fw2    = (const float*)d_in[20];
    const float* fb2    = (const float*)d_in[21];
    const float* fw3    = (const float*)d_in[22];
    const float* fb3    = (const float*)d_in[23];
    float* out = (float*)d_out;

    char* p = (char*)d_ws;
    auto alloc = [&](size_t bytes) -> char* {
        char* r = p;
        p += (bytes + 255) & ~(size_t)255;
        return r;
    };
    float* h0      = (float*)alloc((size_t)NN * CC * 4);
    float* h1      = (float*)alloc((size_t)NN * CC * 4);
    float* hh      = (float*)alloc((size_t)NN * 256 * 4);
    float* lsb     = (float*)alloc((size_t)NN * 2 * 4);
    float* ldb     = (float*)alloc((size_t)NN * 2 * 4);
    int*   deg     = (int*)alloc((size_t)NN * 4);
    int*   row_ptr = (int*)alloc((size_t)(NN + 1) * 4);
    int*   cursor  = (int*)alloc((size_t)NN * 4);
    int*   bsum    = (int*)alloc(1024);
    int*   csr_src = (int*)alloc((size_t)EE * 4);
    float* csr_a1  = (float*)alloc((size_t)EE * 4);
    float* csr_a2  = (float*)alloc((size_t)EE * 4);
    float* wd      = (float*)alloc(256);
    float* obuf    = (float*)alloc((size_t)GG * 256 * 4);

    const int NB = (NN + 255) / 256;  // 157

    // CSR by dst
    hipMemsetAsync(deg, 0, (size_t)NN * 4, stream);
    k_hist<<<(EE + 255) / 256, 256, 0, stream>>>(ei + EE, deg);
    k_scanA<<<NB, 256, 0, stream>>>(deg, row_ptr + 1, bsum);
    k_scanB<<<1, 256, 0, stream>>>(bsum, NB);
    k_scanC<<<NB, 256, 0, stream>>>(row_ptr, bsum);
    k_copycur<<<NB, 256, 0, stream>>>(row_ptr, cursor);
    k_scatter<<<(EE + 255) / 256, 256, 0, stream>>>(ei, ea, mu, devp, cursor, csr_src, csr_a1, csr_a2);
    k_wedot<<<1, 64, 0, stream>>>(We, att_e, wd);

    // embed
    k_embed<<<NN, 128, 0, stream>>>(x, W_emb, h0);

    float* hc = h0;
    float* hn = h1;
    for (int k = 0; k < 3; ++k) {
        k_gemm<<<NN / 32, 256, 0, stream>>>(hc, Wg + (size_t)k * 128 * 256, hh);
        k_lsld<<<(NN * 2) / 4, 256, 0, stream>>>(hh, att_s + k * 256, att_d + k * 256, lsb, ldb);
        k_attn<<<NN / 4, 256, 0, stream>>>(hh, hc, lsb, ldb, row_ptr, csr_src, csr_a1, csr_a2,
                                           wd + k * 2, bg + k * 128, gw + k * 256, gb + k, hn);
        float* tmp = hc; hc = hn; hn = tmp;
    }

    k_readout<<<GG, 128, 0, stream>>>(hc, valid, batch, obuf);
    k_mlp<<<GG, 128, 0, stream>>>(obuf, fw0, fb0, fw1, fb1, fw2, fb2, fw3, fb3, out);
}

// Round 4
// 597.412 us; speedup vs baseline: 1.0647x; 1.0647x over previous
//
#include <hip/hip_runtime.h>
#include <math.h>

#define NN 40000
#define EE 500000
#define CC 128
#define GG 800
#define FINN 56
#define NEGS 0.2f

__device__ __forceinline__ float lrelu(float x) { return x > 0.f ? x : NEGS * x; }

// ---------------- CSR build ----------------
__global__ void k_hist(const int* __restrict__ dst, int* __restrict__ deg) {
    int e = blockIdx.x * 256 + threadIdx.x;
    if (e < EE) atomicAdd(&deg[dst[e]], 1);
}

__global__ void k_scanA(const int* __restrict__ deg, int* __restrict__ row1, int* __restrict__ bsum) {
    __shared__ int buf[256];
    int i = blockIdx.x * 256 + threadIdx.x;
    int v = (i < NN) ? deg[i] : 0;
    buf[threadIdx.x] = v;
    __syncthreads();
    for (int off = 1; off < 256; off <<= 1) {
        int t = (threadIdx.x >= off) ? buf[threadIdx.x - off] : 0;
        __syncthreads();
        buf[threadIdx.x] += t;
        __syncthreads();
    }
    if (i < NN) row1[i] = buf[threadIdx.x];
    if (threadIdx.x == 255) bsum[blockIdx.x] = buf[255];
}

__global__ void k_scanB(int* bsum, int nb) {
    __shared__ int buf[256];
    int v = (threadIdx.x < nb) ? bsum[threadIdx.x] : 0;
    buf[threadIdx.x] = v;
    __syncthreads();
    for (int off = 1; off < 256; off <<= 1) {
        int t = (threadIdx.x >= off) ? buf[threadIdx.x - off] : 0;
        __syncthreads();
        buf[threadIdx.x] += t;
        __syncthreads();
    }
    if (threadIdx.x < nb) bsum[threadIdx.x] = buf[threadIdx.x] - v;  // exclusive
}

__global__ void k_scanC(int* __restrict__ row_ptr, const int* __restrict__ bsum) {
    int i = blockIdx.x * 256 + threadIdx.x;
    if (i < NN) row_ptr[i + 1] += bsum[blockIdx.x];
    if (i == 0) row_ptr[0] = 0;
}

__global__ void k_copycur(const int* __restrict__ row_ptr, int* __restrict__ cursor) {
    int i = blockIdx.x * 256 + threadIdx.x;
    if (i < NN) cursor[i] = row_ptr[i];
}

// interleaved CSR record: {src, a1 bits, a2 bits, pad}
__global__ void k_scatter(const int* __restrict__ ei, const float* __restrict__ ea,
                          const float* __restrict__ mu, const float* __restrict__ dev,
                          int* __restrict__ cursor, int4* __restrict__ csr) {
    int e = blockIdx.x * 256 + threadIdx.x;
    if (e >= EE) return;
    int s = ei[e], d = ei[EE + e];
    float a1 = ea[2 * e];
    float xx = ea[2 * e + 1] - mu[0];
    float a2 = __expf(-xx * xx / dev[0]) + a1;
    int p = atomicAdd(&cursor[d], 1);
    csr[p] = make_int4(s, __float_as_int(a1), __float_as_int(a2), 0);
}

// we_dot[k*2+h] = sum_c We[k,0,h*128+c] * att_e[k,h,c]
__global__ void k_wedot(const float* __restrict__ We, const float* __restrict__ ate, float* __restrict__ wd) {
    int lane = threadIdx.x;  // 64
    for (int idx = 0; idx < 6; ++idx) {
        const float* w = We + idx * 128;
        const float* a = ate + idx * 128;
        float p = w[lane] * a[lane] + w[lane + 64] * a[lane + 64];
        #pragma unroll
        for (int m = 32; m; m >>= 1) p += __shfl_xor(p, m);
        if (lane == 0) wd[idx] = p;
    }
}

// ---------------- embed: h = x @ W_emb  (N,56)@(56,128) ----------------
__global__ __launch_bounds__(128) void k_embed(const float* __restrict__ x, const float* __restrict__ W,
                                               float* __restrict__ h) {
    __shared__ float xs[FINN];
    int n = blockIdx.x, t = threadIdx.x;
    if (t < FINN) xs[t] = x[n * FINN + t];
    __syncthreads();
    float acc = 0.f;
    #pragma unroll
    for (int f = 0; f < FINN; ++f) acc += xs[f] * W[f * CC + t];
    h[n * CC + t] = acc;
}

// ---------------- hh = h @ Wg[k] (N,128)@(128,256), fused ls/ld epilogue ----------------
// lsld[n*4] = {ls0, ls1, ld0, ld1}
__global__ __launch_bounds__(256) void k_gemm(const float* __restrict__ A, const float* __restrict__ W,
                                              const float* __restrict__ as_, const float* __restrict__ ad_,
                                              float* __restrict__ Bout, float* __restrict__ lsld) {
    __shared__ float aT[32][36];    // [k][row], padded
    __shared__ float wT[32][256];   // [k][col]
    float acc[8][4] = {};
    int tid = threadIdx.x;
    int cg = tid & 63;   // col group (4 cols) == lane
    int rg = tid >> 6;   // row group (8 rows) == wave id
    int row0 = blockIdx.x * 32;
    for (int kc = 0; kc < 4; ++kc) {
        {
            int r = tid >> 3, c0 = (tid & 7) * 4;
            float4 v = *(const float4*)&A[(row0 + r) * CC + kc * 32 + c0];
            aT[c0 + 0][r] = v.x; aT[c0 + 1][r] = v.y; aT[c0 + 2][r] = v.z; aT[c0 + 3][r] = v.w;
        }
        #pragma unroll
        for (int i = 0; i < 8; ++i) {
            int flat = i * 1024 + tid * 4;
            int wr = flat >> 8, wc = flat & 255;
            *(float4*)&wT[wr][wc] = *(const float4*)&W[(kc * 32 + wr) * 256 + wc];
        }
        __syncthreads();
        #pragma unroll
        for (int kk = 0; kk < 32; ++kk) {
            float a0[8];
            #pragma unroll
            for (int i = 0; i < 8; ++i) a0[i] = aT[kk][rg * 8 + i];
            float4 w4 = *(const float4*)&wT[kk][cg * 4];
            #pragma unroll
            for (int i = 0; i < 8; ++i) {
                acc[i][0] += a0[i] * w4.x; acc[i][1] += a0[i] * w4.y;
                acc[i][2] += a0[i] * w4.z; acc[i][3] += a0[i] * w4.w;
            }
        }
        __syncthreads();
    }
    float4 as4 = *(const float4*)&as_[cg * 4];
    float4 ad4 = *(const float4*)&ad_[cg * 4];
    #pragma unroll
    for (int i = 0; i < 8; ++i) {
        int row = row0 + rg * 8 + i;
        float4 o = make_float4(acc[i][0], acc[i][1], acc[i][2], acc[i][3]);
        *(float4*)&Bout[row * 256 + cg * 4] = o;
        // ls/ld partials: this lane's 4 cols are all within one head (head = cg>>5)
        float ps = o.x * as4.x + o.y * as4.y + o.z * as4.z + o.w * as4.w;
        float pd = o.x * ad4.x + o.y * ad4.y + o.z * ad4.z + o.w * ad4.w;
        #pragma unroll
        for (int m = 16; m; m >>= 1) { ps += __shfl_xor(ps, m); pd += __shfl_xor(pd, m); }
        if ((cg & 31) == 0) {
            int hidx = cg >> 5;
            lsld[row * 4 + hidx] = ps;
            lsld[row * 4 + 2 + hidx] = pd;
        }
    }
}

// ---------------- fused attention (both gates), single pass, no max-sub ----------------
__global__ __launch_bounds__(256) void k_attn(
    const float* __restrict__ hh, const float* __restrict__ hcur,
    const float* __restrict__ lsld,
    const int* __restrict__ row_ptr, const int4* __restrict__ csr,
    const float* __restrict__ wd, const float* __restrict__ bg,
    const float* __restrict__ gw, const float* __restrict__ gb,
    float* __restrict__ hout) {
    __shared__ float ev[4][64][4];   // [wave][edge-in-chunk][e00,e01,e10,e11]
    int wid = threadIdx.x >> 6, lane = threadIdx.x & 63;
    int n = blockIdx.x * 4 + wid;    // NN % 4 == 0, always valid
    float wd0 = wd[0], wd1 = wd[1];
    float4 nld = *(const float4*)&lsld[n * 4];
    float ld0 = nld.z, ld1 = nld.w;
    int jbeg = __builtin_amdgcn_readfirstlane(row_ptr[n]);
    int jend = __builtin_amdgcn_readfirstlane(row_ptr[n + 1]);
    int hd = lane >> 5;              // head owned
    int cb = lane & 31;              // float4 group within head
    int voff = hd * 32 + cb;         // float4 index within hh row (64 per row)
    const float4* hh4 = (const float4*)hh;
    const float* evp = &ev[wid][0][hd * 2];
    float s0 = 0, s1 = 0, s2 = 0, s3 = 0;
    float acc1[4] = {0, 0, 0, 0}, acc2[4] = {0, 0, 0, 0};

    for (int j0 = jbeg; j0 < jend; j0 += 64) {
        int j = j0 + lane;
        int nact = min(64, jend - j0);
        float4 e4 = make_float4(0.f, 0.f, 0.f, 0.f);
        if (j < jend) {
            int4 c = csr[j];
            float a1 = __int_as_float(c.y), a2 = __int_as_float(c.z);
            float2 lsv = *(const float2*)&lsld[c.x * 4];
            float b0 = lsv.x + ld0, b1 = lsv.y + ld1;
            e4.x = __expf(fminf(lrelu(b0 + a1 * wd0), 80.f));
            e4.y = __expf(fminf(lrelu(b0 + a2 * wd0), 80.f));
            e4.z = __expf(fminf(lrelu(b1 + a1 * wd1), 80.f));
            e4.w = __expf(fminf(lrelu(b1 + a2 * wd1), 80.f));
            s0 += e4.x; s1 += e4.y; s2 += e4.z; s3 += e4.w;
        }
        *(float4*)&ev[wid][lane][0] = e4;
        #pragma unroll 4
        for (int jj = 0; jj < nact; ++jj) {
            int s = csr[j0 + jj].x;                       // wave-uniform -> s_load
            float2 ef = *(const float2*)&evp[jj * 4];     // LDS broadcast per half-wave
            float4 v = hh4[s * 64 + voff];                // saddr + const voffset
            acc1[0] += ef.x * v.x; acc1[1] += ef.x * v.y;
            acc1[2] += ef.x * v.z; acc1[3] += ef.x * v.w;
            acc2[0] += ef.y * v.x; acc2[1] += ef.y * v.y;
            acc2[2] += ef.y * v.z; acc2[3] += ef.y * v.w;
        }
    }
    #pragma unroll
    for (int m = 32; m; m >>= 1) {
        s0 += __shfl_xor(s0, m); s1 += __shfl_xor(s1, m);
        s2 += __shfl_xor(s2, m); s3 += __shfl_xor(s3, m);
    }
    float d1 = (hd ? s2 : s0) + 1e-16f;
    float d2 = (hd ? s3 : s1) + 1e-16f;
    int cbase = cb * 4;
    float o1[4], o2[4];
    #pragma unroll
    for (int i = 0; i < 4; ++i) { o1[i] = acc1[i] / d1; o2[i] = acc2[i] / d2; }
    #pragma unroll
    for (int i = 0; i < 4; ++i) {
        o1[i] = 0.5f * (o1[i] + __shfl_xor(o1[i], 32)) + bg[cbase + i];
        o2[i] = 0.5f * (o2[i] + __shfl_xor(o2[i], 32)) + bg[cbase + i];
    }
    float4 h4 = ((const float4*)hcur)[n * 32 + cb];
    float p1 = 0, p2 = 0;
    if (hd == 0) {
        #pragma unroll
        for (int i = 0; i < 4; ++i) {
            p1 += o1[i] * gw[128 + cbase + i];
            p2 += o2[i] * gw[128 + cbase + i];
        }
    } else {
        float hp = h4.x * gw[cbase] + h4.y * gw[cbase + 1] + h4.z * gw[cbase + 2] + h4.w * gw[cbase + 3];
        p1 = hp; p2 = hp;
    }
    #pragma unroll
    for (int m = 32; m; m >>= 1) { p1 += __shfl_xor(p1, m); p2 += __shfl_xor(p2, m); }
    float z1 = 1.f / (1.f + __expf(-(p1 + gb[0])));
    float z2 = 1.f / (1.f + __expf(-(p2 + gb[0])));
    if (hd == 0) {
        float hv[4] = {h4.x, h4.y, h4.z, h4.w};
        float r[4];
        #pragma unroll
        for (int i = 0; i < 4; ++i) {
            float g1 = z1 * hv[i] + (1.f - z1) * fmaxf(o1[i], 0.f);
            float g2 = z2 * hv[i] + (1.f - z2) * fmaxf(o2[i], 0.f);
            r[i] = g2 - g1;
        }
        ((float4*)hout)[n * 32 + cb] = make_float4(r[0], r[1], r[2], r[3]);
    }
}

// ---------------- readout: segment sums over sorted batch_idx ----------------
__global__ __launch_bounds__(128) void k_readout(const float* __restrict__ h, const float* __restrict__ valid,
                                                 const int* __restrict__ batch, float* __restrict__ obuf) {
    int g = blockIdx.x, t = threadIdx.x;
    int lo = 0, hi = NN;
    while (lo < hi) { int mid = (lo + hi) >> 1; if (batch[mid] < g) lo = mid + 1; else hi = mid; }
    int s = lo;
    lo = s; hi = NN;
    while (lo < hi) { int mid = (lo + hi) >> 1; if (batch[mid] < g + 1) lo = mid + 1; else hi = mid; }
    int e = lo;
    float gl = 0, gp = 0;
    for (int n = s; n < e; ++n) {
        float hv = h[n * CC + t];
        gl += hv * valid[n * 2];
        gp += hv * valid[n * 2 + 1];
    }
    obuf[g * 256 + t] = gl;
    obuf[g * 256 + 128 + t] = gp;
}

// ---------------- per-graph MLP ----------------
__global__ __launch_bounds__(128) void k_mlp(const float* __restrict__ obuf,
    const float* __restrict__ w0, const float* __restrict__ b0,
    const float* __restrict__ w1, const float* __restrict__ b1,
    const float* __restrict__ w2, const float* __restrict__ b2,
    const float* __restrict__ w3, const float* __restrict__ b3,
    float* __restrict__ out) {
    __shared__ float cur[256];
    __shared__ float nxt[128];
    int g = blockIdx.x, t = threadIdx.x;
    cur[t] = obuf[g * 256 + t];
    cur[t + 128] = obuf[g * 256 + 128 + t];
    __syncthreads();
    float s = b0[t];
    for (int i = 0; i < 256; ++i) s += cur[i] * w0[i * 128 + t];
    nxt[t] = fmaxf(s, 0.f);
    __syncthreads();
    s = b1[t];
    for (int i = 0; i < 128; ++i) s += nxt[i] * w1[i * 128 + t];
    cur[t] = fmaxf(s, 0.f);
    __syncthreads();
    s = b2[t];
    for (int i = 0; i < 128; ++i) s += cur[i] * w2[i * 128 + t];
    nxt[t] = fmaxf(s, 0.f);
    __syncthreads();
    if (t < 2) {
        float o = b3[t];
        for (int i = 0; i < 128; ++i) o += nxt[i] * w3[i * 2 + t];
        out[g * 2 + t] = (t == 1) ? expf(o) : o;
    }
}

extern "C" void kernel_launch(void* const* d_in, const int* in_sizes, int n_in,
                              void* d_out, int out_size, void* d_ws, size_t ws_size,
                              hipStream_t stream) {
    const float* x      = (const float*)d_in[0];
    const int*   ei     = (const int*)d_in[1];
    const float* ea     = (const float*)d_in[2];
    const float* valid  = (const float*)d_in[3];
    const int*   batch  = (const int*)d_in[4];
    const float* mu     = (const float*)d_in[5];
    const float* devp   = (const float*)d_in[6];
    const float* W_emb  = (const float*)d_in[7];
    const float* Wg     = (const float*)d_in[8];
    const float* att_s  = (const float*)d_in[9];
    const float* att_d  = (const float*)d_in[10];
    const float* We     = (const float*)d_in[11];
    const float* att_e  = (const float*)d_in[12];
    const float* bg     = (const float*)d_in[13];
    const float* gw     = (const float*)d_in[14];
    const float* gb     = (const float*)d_in[15];
    const float* fw0    = (const float*)d_in[16];
    const float* fb0    = (const float*)d_in[17];
    const float* fw1    = (const float*)d_in[18];
    const float* fb1    = (const float*)d_in[19];
    const float* fw2    = (const float*)d_in[20];
    const float* fb2    = (const float*)d_in[21];
    const float* fw3    = (const float*)d_in[22];
    const float* fb3    = (const float*)d_in[23];
    float* out = (float*)d_out;

    char* p = (char*)d_ws;
    auto alloc = [&](size_t bytes) -> char* {
        char* r = p;
        p += (bytes + 255) & ~(size_t)255;
        return r;
    };
    float* h0      = (float*)alloc((size_t)NN * CC * 4);
    float* h1      = (float*)alloc((size_t)NN * CC * 4);
    float* hh      = (float*)alloc((size_t)NN * 256 * 4);
    float* lsld    = (float*)alloc((size_t)NN * 4 * 4);
    int*   deg     = (int*)alloc((size_t)NN * 4);
    int*   row_ptr = (int*)alloc((size_t)(NN + 1) * 4);
    int*   cursor  = (int*)alloc((size_t)NN * 4);
    int*   bsum    = (int*)alloc(1024);
    int4*  csr     = (int4*)alloc((size_t)EE * 16);
    float* wd      = (float*)alloc(256);
    float* obuf    = (float*)alloc((size_t)GG * 256 * 4);

    const int NB = (NN + 255) / 256;  // 157

    // CSR by dst
    hipMemsetAsync(deg, 0, (size_t)NN * 4, stream);
    k_hist<<<(EE + 255) / 256, 256, 0, stream>>>(ei + EE, deg);
    k_scanA<<<NB, 256, 0, stream>>>(deg, row_ptr + 1, bsum);
    k_scanB<<<1, 256, 0, stream>>>(bsum, NB);
    k_scanC<<<NB, 256, 0, stream>>>(row_ptr, bsum);
    k_copycur<<<NB, 256, 0, stream>>>(row_ptr, cursor);
    k_scatter<<<(EE + 255) / 256, 256, 0, stream>>>(ei, ea, mu, devp, cursor, csr);
    k_wedot<<<1, 64, 0, stream>>>(We, att_e, wd);

    // embed
    k_embed<<<NN, 128, 0, stream>>>(x, W_emb, h0);

    float* hc = h0;
    float* hn = h1;
    for (int k = 0; k < 3; ++k) {
        k_gemm<<<NN / 32, 256, 0, stream>>>(hc, Wg + (size_t)k * 128 * 256,
                                            att_s + k * 256, att_d + k * 256, hh, lsld);
        k_attn<<<NN / 4, 256, 0, stream>>>(hh, hc, lsld, row_ptr, csr,
                                           wd + k * 2, bg + k * 128, gw + k * 256, gb + k, hn);
        float* tmp = hc; hc = hn; hn = tmp;
    }

    k_readout<<<GG, 128, 0, stream>>>(hc, valid, batch, obuf);
    k_mlp<<<GG, 128, 0, stream>>>(obuf, fw0, fb0, fw1, fb1, fw2, fb2, fw3, fb3, out);
}

// Round 5
// 532.190 us; speedup vs baseline: 1.1952x; 1.1226x over previous
//
#include <hip/hip_runtime.h>
#include <hip/hip_fp16.h>
#include <math.h>

#define NN 40000
#define EE 500000
#define CC 128
#define GG 800
#define FINN 56
#define NEGS 0.2f

__device__ __forceinline__ float lrelu(float x) { return x > 0.f ? x : NEGS * x; }

// ---------------- CSR build ----------------
__global__ void k_hist(const int* __restrict__ dst, int* __restrict__ deg) {
    int e = blockIdx.x * 256 + threadIdx.x;
    if (e < EE) atomicAdd(&deg[dst[e]], 1);
}

__global__ void k_scanA(const int* __restrict__ deg, int* __restrict__ row1, int* __restrict__ bsum) {
    __shared__ int buf[256];
    int i = blockIdx.x * 256 + threadIdx.x;
    int v = (i < NN) ? deg[i] : 0;
    buf[threadIdx.x] = v;
    __syncthreads();
    for (int off = 1; off < 256; off <<= 1) {
        int t = (threadIdx.x >= off) ? buf[threadIdx.x - off] : 0;
        __syncthreads();
        buf[threadIdx.x] += t;
        __syncthreads();
    }
    if (i < NN) row1[i] = buf[threadIdx.x];
    if (threadIdx.x == 255) bsum[blockIdx.x] = buf[255];
}

__global__ void k_scanB(int* bsum, int nb) {
    __shared__ int buf[256];
    int v = (threadIdx.x < nb) ? bsum[threadIdx.x] : 0;
    buf[threadIdx.x] = v;
    __syncthreads();
    for (int off = 1; off < 256; off <<= 1) {
        int t = (threadIdx.x >= off) ? buf[threadIdx.x - off] : 0;
        __syncthreads();
        buf[threadIdx.x] += t;
        __syncthreads();
    }
    if (threadIdx.x < nb) bsum[threadIdx.x] = buf[threadIdx.x] - v;  // exclusive
}

__global__ void k_scanC(int* __restrict__ row_ptr, const int* __restrict__ bsum) {
    int i = blockIdx.x * 256 + threadIdx.x;
    if (i < NN) row_ptr[i + 1] += bsum[blockIdx.x];
    if (i == 0) row_ptr[0] = 0;
}

__global__ void k_copycur(const int* __restrict__ row_ptr, int* __restrict__ cursor) {
    int i = blockIdx.x * 256 + threadIdx.x;
    if (i < NN) cursor[i] = row_ptr[i];
}

// interleaved CSR record: {src, a1 bits, a2 bits, pad}
__global__ void k_scatter(const int* __restrict__ ei, const float* __restrict__ ea,
                          const float* __restrict__ mu, const float* __restrict__ dev,
                          int* __restrict__ cursor, int4* __restrict__ csr) {
    int e = blockIdx.x * 256 + threadIdx.x;
    if (e >= EE) return;
    int s = ei[e], d = ei[EE + e];
    float a1 = ea[2 * e];
    float xx = ea[2 * e + 1] - mu[0];
    float a2 = __expf(-xx * xx / dev[0]) + a1;
    int p = atomicAdd(&cursor[d], 1);
    csr[p] = make_int4(s, __float_as_int(a1), __float_as_int(a2), 0);
}

// we_dot[k*2+h] = sum_c We[k,0,h*128+c] * att_e[k,h,c]
__global__ void k_wedot(const float* __restrict__ We, const float* __restrict__ ate, float* __restrict__ wd) {
    int lane = threadIdx.x;  // 64
    for (int idx = 0; idx < 6; ++idx) {
        const float* w = We + idx * 128;
        const float* a = ate + idx * 128;
        float p = w[lane] * a[lane] + w[lane + 64] * a[lane + 64];
        #pragma unroll
        for (int m = 32; m; m >>= 1) p += __shfl_xor(p, m);
        if (lane == 0) wd[idx] = p;
    }
}

// ---------------- embed: h = x @ W_emb  (N,56)@(56,128) ----------------
__global__ __launch_bounds__(128) void k_embed(const float* __restrict__ x, const float* __restrict__ W,
                                               float* __restrict__ h) {
    __shared__ float xs[FINN];
    int n = blockIdx.x, t = threadIdx.x;
    if (t < FINN) xs[t] = x[n * FINN + t];
    __syncthreads();
    float acc = 0.f;
    #pragma unroll
    for (int f = 0; f < FINN; ++f) acc += xs[f] * W[f * CC + t];
    h[n * CC + t] = acc;
}

// ---------------- hh = h @ Wg[k] (N,128)@(128,256) -> fp16 table, fused ls/ld ----------------
// lsld[n*4] = {ls0, ls1, ld0, ld1}
__global__ __launch_bounds__(256) void k_gemm(const float* __restrict__ A, const float* __restrict__ W,
                                              const float* __restrict__ as_, const float* __restrict__ ad_,
                                              __half* __restrict__ hh16, float* __restrict__ lsld) {
    __shared__ float aT[32][36];    // [k][row], padded
    __shared__ float wT[32][256];   // [k][col]
    float acc[8][4] = {};
    int tid = threadIdx.x;
    int cg = tid & 63;   // col group (4 cols) == lane
    int rg = tid >> 6;   // row group (8 rows) == wave id
    int row0 = blockIdx.x * 32;
    for (int kc = 0; kc < 4; ++kc) {
        {
            int r = tid >> 3, c0 = (tid & 7) * 4;
            float4 v = *(const float4*)&A[(row0 + r) * CC + kc * 32 + c0];
            aT[c0 + 0][r] = v.x; aT[c0 + 1][r] = v.y; aT[c0 + 2][r] = v.z; aT[c0 + 3][r] = v.w;
        }
        #pragma unroll
        for (int i = 0; i < 8; ++i) {
            int flat = i * 1024 + tid * 4;
            int wr = flat >> 8, wc = flat & 255;
            *(float4*)&wT[wr][wc] = *(const float4*)&W[(kc * 32 + wr) * 256 + wc];
        }
        __syncthreads();
        #pragma unroll
        for (int kk = 0; kk < 32; ++kk) {
            float a0[8];
            #pragma unroll
            for (int i = 0; i < 8; ++i) a0[i] = aT[kk][rg * 8 + i];
            float4 w4 = *(const float4*)&wT[kk][cg * 4];
            #pragma unroll
            for (int i = 0; i < 8; ++i) {
                acc[i][0] += a0[i] * w4.x; acc[i][1] += a0[i] * w4.y;
                acc[i][2] += a0[i] * w4.z; acc[i][3] += a0[i] * w4.w;
            }
        }
        __syncthreads();
    }
    float4 as4 = *(const float4*)&as_[cg * 4];
    float4 ad4 = *(const float4*)&ad_[cg * 4];
    #pragma unroll
    for (int i = 0; i < 8; ++i) {
        int row = row0 + rg * 8 + i;
        float4 o = make_float4(acc[i][0], acc[i][1], acc[i][2], acc[i][3]);
        // fp16 store (4 halves = 8B)
        __half2 q0, q1;
        q0.x = __float2half_rn(o.x); q0.y = __float2half_rn(o.y);
        q1.x = __float2half_rn(o.z); q1.y = __float2half_rn(o.w);
        uint2 pk = make_uint2(*(unsigned*)&q0, *(unsigned*)&q1);
        *(uint2*)&hh16[row * 256 + cg * 4] = pk;
        // ls/ld partials: this lane's 4 cols are all within one head (head = cg>>5)
        float ps = o.x * as4.x + o.y * as4.y + o.z * as4.z + o.w * as4.w;
        float pd = o.x * ad4.x + o.y * ad4.y + o.z * ad4.z + o.w * ad4.w;
        #pragma unroll
        for (int m = 16; m; m >>= 1) { ps += __shfl_xor(ps, m); pd += __shfl_xor(pd, m); }
        if ((cg & 31) == 0) {
            int hidx = cg >> 5;
            lsld[row * 4 + hidx] = ps;
            lsld[row * 4 + 2 + hidx] = pd;
        }
    }
}

// ---------------- fused attention (both gates), fp16 gather, 2 edges/iter ----------------
__global__ __launch_bounds__(256) void k_attn(
    const __half* __restrict__ hh16, const float* __restrict__ hcur,
    const float* __restrict__ lsld,
    const int* __restrict__ row_ptr, const int4* __restrict__ csr,
    const float* __restrict__ wd, const float* __restrict__ bg,
    const float* __restrict__ gw, const float* __restrict__ gb,
    float* __restrict__ hout) {
    __shared__ float ev[4][64][2][4];   // [wave][edge][head]{e_g1, e_g2, src_bits, pad}
    int wid = threadIdx.x >> 6, lane = threadIdx.x & 63;
    int n = blockIdx.x * 4 + wid;       // NN % 4 == 0
    float wd0 = wd[0], wd1 = wd[1];
    float4 nld = *(const float4*)&lsld[n * 4];
    float ld0 = nld.z, ld1 = nld.w;
    int jbeg = __builtin_amdgcn_readfirstlane(row_ptr[n]);
    int jend = __builtin_amdgcn_readfirstlane(row_ptr[n + 1]);
    int grp  = lane >> 5;               // which edge of the pair
    int sub  = lane & 31;               // channel group: 8 ch at sub*8
    int hd01 = sub >> 4;                // head for my channels
    float s0 = 0, s1 = 0, s2 = 0, s3 = 0;
    float acc1[8] = {0,0,0,0,0,0,0,0}, acc2[8] = {0,0,0,0,0,0,0,0};

    for (int j0 = jbeg; j0 < jend; j0 += 64) {
        int j = j0 + lane;
        int nact = min(64, jend - j0);
        float4 e4 = make_float4(0.f, 0.f, 0.f, 0.f);
        int smine = 0;
        if (j < jend) {
            int4 c = csr[j];
            smine = c.x;
            float a1 = __int_as_float(c.y), a2 = __int_as_float(c.z);
            float2 lsv = *(const float2*)&lsld[smine * 4];
            float b0 = lsv.x + ld0, b1 = lsv.y + ld1;
            e4.x = __expf(fminf(lrelu(b0 + a1 * wd0), 80.f));
            e4.y = __expf(fminf(lrelu(b0 + a2 * wd0), 80.f));
            e4.z = __expf(fminf(lrelu(b1 + a1 * wd1), 80.f));
            e4.w = __expf(fminf(lrelu(b1 + a2 * wd1), 80.f));
            s0 += e4.x; s1 += e4.y; s2 += e4.z; s3 += e4.w;
        }
        float sf = __int_as_float(smine);
        *(float4*)&ev[wid][lane][0][0] = make_float4(e4.x, e4.y, sf, 0.f);
        *(float4*)&ev[wid][lane][1][0] = make_float4(e4.z, e4.w, sf, 0.f);
        int it = (nact + 1) >> 1;
        #pragma unroll 2
        for (int jj = 0; jj < it; ++jj) {
            int ed = 2 * jj + grp;
            float4 em = *(const float4*)&ev[wid][ed][hd01][0];
            int s = __float_as_int(em.z);
            uint4 raw = *(const uint4*)(hh16 + s * 256 + sub * 8);
            float2 f0 = __half22float2(*(__half2*)&raw.x);
            float2 f1 = __half22float2(*(__half2*)&raw.y);
            float2 f2 = __half22float2(*(__half2*)&raw.z);
            float2 f3 = __half22float2(*(__half2*)&raw.w);
            acc1[0] += em.x * f0.x; acc1[1] += em.x * f0.y;
            acc1[2] += em.x * f1.x; acc1[3] += em.x * f1.y;
            acc1[4] += em.x * f2.x; acc1[5] += em.x * f2.y;
            acc1[6] += em.x * f3.x; acc1[7] += em.x * f3.y;
            acc2[0] += em.y * f0.x; acc2[1] += em.y * f0.y;
            acc2[2] += em.y * f1.x; acc2[3] += em.y * f1.y;
            acc2[4] += em.y * f2.x; acc2[5] += em.y * f2.y;
            acc2[6] += em.y * f3.x; acc2[7] += em.y * f3.y;
        }
    }
    // combine the two edge-groups (lane l and l^32 hold same channels)
    #pragma unroll
    for (int i = 0; i < 8; ++i) {
        acc1[i] += __shfl_xor(acc1[i], 32);
        acc2[i] += __shfl_xor(acc2[i], 32);
    }
    #pragma unroll
    for (int m = 32; m; m >>= 1) {
        s0 += __shfl_xor(s0, m); s1 += __shfl_xor(s1, m);
        s2 += __shfl_xor(s2, m); s3 += __shfl_xor(s3, m);
    }
    float d1 = (hd01 ? s2 : s0) + 1e-16f;
    float d2 = (hd01 ? s3 : s1) + 1e-16f;
    int c0 = (sub & 15) * 8;            // within-head channel base (also output channel base)
    float o1[8], o2[8];
    #pragma unroll
    for (int i = 0; i < 8; ++i) { o1[i] = acc1[i] / d1; o2[i] = acc2[i] / d2; }
    // head-mean: partner lane sub^16 holds the other head's same within-head channels
    #pragma unroll
    for (int i = 0; i < 8; ++i) {
        o1[i] = 0.5f * (o1[i] + __shfl_xor(o1[i], 16)) + bg[c0 + i];
        o2[i] = 0.5f * (o2[i] + __shfl_xor(o2[i], 16)) + bg[c0 + i];
    }
    float hv[8];
    *(float4*)&hv[0] = ((const float4*)hcur)[n * 32 + (sub & 15) * 2];
    *(float4*)&hv[4] = ((const float4*)hcur)[n * 32 + (sub & 15) * 2 + 1];
    float pp1 = 0.f, pp2 = 0.f;
    if (lane < 16) {
        #pragma unroll
        for (int i = 0; i < 8; ++i) {
            pp1 += o1[i] * gw[128 + c0 + i];
            pp2 += o2[i] * gw[128 + c0 + i];
        }
    } else if (lane < 32) {
        float hp = 0.f;
        #pragma unroll
        for (int i = 0; i < 8; ++i) hp += hv[i] * gw[c0 + i];
        pp1 = hp; pp2 = hp;
    }
    #pragma unroll
    for (int m = 32; m; m >>= 1) { pp1 += __shfl_xor(pp1, m); pp2 += __shfl_xor(pp2, m); }
    float z1 = 1.f / (1.f + __expf(-(pp1 + gb[0])));
    float z2 = 1.f / (1.f + __expf(-(pp2 + gb[0])));
    if (lane < 16) {
        float r[8];
        #pragma unroll
        for (int i = 0; i < 8; ++i) {
            float g1 = z1 * hv[i] + (1.f - z1) * fmaxf(o1[i], 0.f);
            float g2 = z2 * hv[i] + (1.f - z2) * fmaxf(o2[i], 0.f);
            r[i] = g2 - g1;
        }
        ((float4*)hout)[n * 32 + (sub & 15) * 2]     = make_float4(r[0], r[1], r[2], r[3]);
        ((float4*)hout)[n * 32 + (sub & 15) * 2 + 1] = make_float4(r[4], r[5], r[6], r[7]);
    }
}

// ---------------- readout: segment sums over sorted batch_idx ----------------
__global__ __launch_bounds__(128) void k_readout(const float* __restrict__ h, const float* __restrict__ valid,
                                                 const int* __restrict__ batch, float* __restrict__ obuf) {
    int g = blockIdx.x, t = threadIdx.x;
    int lo = 0, hi = NN;
    while (lo < hi) { int mid = (lo + hi) >> 1; if (batch[mid] < g) lo = mid + 1; else hi = mid; }
    int s = lo;
    lo = s; hi = NN;
    while (lo < hi) { int mid = (lo + hi) >> 1; if (batch[mid] < g + 1) lo = mid + 1; else hi = mid; }
    int e = lo;
    float gl = 0, gp = 0;
    for (int n = s; n < e; ++n) {
        float hv = h[n * CC + t];
        gl += hv * valid[n * 2];
        gp += hv * valid[n * 2 + 1];
    }
    obuf[g * 256 + t] = gl;
    obuf[g * 256 + 128 + t] = gp;
}

// ---------------- per-graph MLP ----------------
__global__ __launch_bounds__(128) void k_mlp(const float* __restrict__ obuf,
    const float* __restrict__ w0, const float* __restrict__ b0,
    const float* __restrict__ w1, const float* __restrict__ b1,
    const float* __restrict__ w2, const float* __restrict__ b2,
    const float* __restrict__ w3, const float* __restrict__ b3,
    float* __restrict__ out) {
    __shared__ float cur[256];
    __shared__ float nxt[128];
    int g = blockIdx.x, t = threadIdx.x;
    cur[t] = obuf[g * 256 + t];
    cur[t + 128] = obuf[g * 256 + 128 + t];
    __syncthreads();
    float s = b0[t];
    for (int i = 0; i < 256; ++i) s += cur[i] * w0[i * 128 + t];
    nxt[t] = fmaxf(s, 0.f);
    __syncthreads();
    s = b1[t];
    for (int i = 0; i < 128; ++i) s += nxt[i] * w1[i * 128 + t];
    cur[t] = fmaxf(s, 0.f);
    __syncthreads();
    s = b2[t];
    for (int i = 0; i < 128; ++i) s += cur[i] * w2[i * 128 + t];
    nxt[t] = fmaxf(s, 0.f);
    __syncthreads();
    if (t < 2) {
        float o = b3[t];
        for (int i = 0; i < 128; ++i) o += nxt[i] * w3[i * 2 + t];
        out[g * 2 + t] = (t == 1) ? expf(o) : o;
    }
}

extern "C" void kernel_launch(void* const* d_in, const int* in_sizes, int n_in,
                              void* d_out, int out_size, void* d_ws, size_t ws_size,
                              hipStream_t stream) {
    const float* x      = (const float*)d_in[0];
    const int*   ei     = (const int*)d_in[1];
    const float* ea     = (const float*)d_in[2];
    const float* valid  = (const float*)d_in[3];
    const int*   batch  = (const int*)d_in[4];
    const float* mu     = (const float*)d_in[5];
    const float* devp   = (const float*)d_in[6];
    const float* W_emb  = (const float*)d_in[7];
    const float* Wg     = (const float*)d_in[8];
    const float* att_s  = (const float*)d_in[9];
    const float* att_d  = (const float*)d_in[10];
    const float* We     = (const float*)d_in[11];
    const float* att_e  = (const float*)d_in[12];
    const float* bg     = (const float*)d_in[13];
    const float* gw     = (const float*)d_in[14];
    const float* gb     = (const float*)d_in[15];
    const float* fw0    = (const float*)d_in[16];
    const float* fb0    = (const float*)d_in[17];
    const float* fw1    = (const float*)d_in[18];
    const float* fb1    = (const float*)d_in[19];
    const float* fw2    = (const float*)d_in[20];
    const float* fb2    = (const float*)d_in[21];
    const float* fw3    = (const float*)d_in[22];
    const float* fb3    = (const float*)d_in[23];
    float* out = (float*)d_out;

    char* p = (char*)d_ws;
    auto alloc = [&](size_t bytes) -> char* {
        char* r = p;
        p += (bytes + 255) & ~(size_t)255;
        return r;
    };
    float*  h0      = (float*)alloc((size_t)NN * CC * 4);
    float*  h1      = (float*)alloc((size_t)NN * CC * 4);
    __half* hh16    = (__half*)alloc((size_t)NN * 256 * 2);
    float*  lsld    = (float*)alloc((size_t)NN * 4 * 4);
    int*    deg     = (int*)alloc((size_t)NN * 4);
    int*    row_ptr = (int*)alloc((size_t)(NN + 1) * 4);
    int*    cursor  = (int*)alloc((size_t)NN * 4);
    int*    bsum    = (int*)alloc(1024);
    int4*   csr     = (int4*)alloc((size_t)EE * 16);
    float*  wd      = (float*)alloc(256);
    float*  obuf    = (float*)alloc((size_t)GG * 256 * 4);

    const int NB = (NN + 255) / 256;  // 157

    // CSR by dst
    hipMemsetAsync(deg, 0, (size_t)NN * 4, stream);
    k_hist<<<(EE + 255) / 256, 256, 0, stream>>>(ei + EE, deg);
    k_scanA<<<NB, 256, 0, stream>>>(deg, row_ptr + 1, bsum);
    k_scanB<<<1, 256, 0, stream>>>(bsum, NB);
    k_scanC<<<NB, 256, 0, stream>>>(row_ptr, bsum);
    k_copycur<<<NB, 256, 0, stream>>>(row_ptr, cursor);
    k_scatter<<<(EE + 255) / 256, 256, 0, stream>>>(ei, ea, mu, devp, cursor, csr);
    k_wedot<<<1, 64, 0, stream>>>(We, att_e, wd);

    // embed
    k_embed<<<NN, 128, 0, stream>>>(x, W_emb, h0);

    float* hc = h0;
    float* hn = h1;
    for (int k = 0; k < 3; ++k) {
        k_gemm<<<NN / 32, 256, 0, stream>>>(hc, Wg + (size_t)k * 128 * 256,
                                            att_s + k * 256, att_d + k * 256, hh16, lsld);
        k_attn<<<NN / 4, 256, 0, stream>>>(hh16, hc, lsld, row_ptr, csr,
                                           wd + k * 2, bg + k * 128, gw + k * 256, gb + k, hn);
        float* tmp = hc; hc = hn; hn = tmp;
    }

    k_readout<<<GG, 128, 0, stream>>>(hc, valid, batch, obuf);
    k_mlp<<<GG, 128, 0, stream>>>(obuf, fw0, fb0, fw1, fb1, fw2, fb2, fw3, fb3, out);
}

// Round 6
// 498.340 us; speedup vs baseline: 1.2764x; 1.0679x over previous
//
#include <hip/hip_runtime.h>
#include <hip/hip_fp16.h>
#include <math.h>

#define NN 40000
#define EE 500000
#define CC 128
#define GG 800
#define FINN 56
#define NEGS 0.2f

typedef _Float16 f16x8 __attribute__((ext_vector_type(8)));
typedef float f32x4 __attribute__((ext_vector_type(4)));

__device__ __forceinline__ float lrelu(float x) { return x > 0.f ? x : NEGS * x; }

// ---------------- CSR build ----------------
__global__ void k_hist(const int* __restrict__ dst, int* __restrict__ deg) {
    int e = blockIdx.x * 256 + threadIdx.x;
    if (e < EE) atomicAdd(&deg[dst[e]], 1);
}

__global__ void k_scanA(const int* __restrict__ deg, int* __restrict__ row1, int* __restrict__ bsum) {
    __shared__ int buf[256];
    int i = blockIdx.x * 256 + threadIdx.x;
    int v = (i < NN) ? deg[i] : 0;
    buf[threadIdx.x] = v;
    __syncthreads();
    for (int off = 1; off < 256; off <<= 1) {
        int t = (threadIdx.x >= off) ? buf[threadIdx.x - off] : 0;
        __syncthreads();
        buf[threadIdx.x] += t;
        __syncthreads();
    }
    if (i < NN) row1[i] = buf[threadIdx.x];
    if (threadIdx.x == 255) bsum[blockIdx.x] = buf[255];
}

__global__ void k_scanB(int* bsum, int nb) {
    __shared__ int buf[256];
    int v = (threadIdx.x < nb) ? bsum[threadIdx.x] : 0;
    buf[threadIdx.x] = v;
    __syncthreads();
    for (int off = 1; off < 256; off <<= 1) {
        int t = (threadIdx.x >= off) ? buf[threadIdx.x - off] : 0;
        __syncthreads();
        buf[threadIdx.x] += t;
        __syncthreads();
    }
    if (threadIdx.x < nb) bsum[threadIdx.x] = buf[threadIdx.x] - v;  // exclusive
}

__global__ void k_scanC(int* __restrict__ row_ptr, const int* __restrict__ bsum) {
    int i = blockIdx.x * 256 + threadIdx.x;
    if (i < NN) row_ptr[i + 1] += bsum[blockIdx.x];
    if (i == 0) row_ptr[0] = 0;
}

__global__ void k_copycur(const int* __restrict__ row_ptr, int* __restrict__ cursor) {
    int i = blockIdx.x * 256 + threadIdx.x;
    if (i < NN) cursor[i] = row_ptr[i];
}

// interleaved CSR record: {src, a1 bits, a2 bits, pad}
__global__ void k_scatter(const int* __restrict__ ei, const float* __restrict__ ea,
                          const float* __restrict__ mu, const float* __restrict__ dev,
                          int* __restrict__ cursor, int4* __restrict__ csr) {
    int e = blockIdx.x * 256 + threadIdx.x;
    if (e >= EE) return;
    int s = ei[e], d = ei[EE + e];
    float a1 = ea[2 * e];
    float xx = ea[2 * e + 1] - mu[0];
    float a2 = __expf(-xx * xx / dev[0]) + a1;
    int p = atomicAdd(&cursor[d], 1);
    csr[p] = make_int4(s, __float_as_int(a1), __float_as_int(a2), 0);
}

// we_dot[k*2+h] = sum_c We[k,0,h*128+c] * att_e[k,h,c]
__global__ void k_wedot(const float* __restrict__ We, const float* __restrict__ ate, float* __restrict__ wd) {
    int lane = threadIdx.x;  // 64
    for (int idx = 0; idx < 6; ++idx) {
        const float* w = We + idx * 128;
        const float* a = ate + idx * 128;
        float p = w[lane] * a[lane] + w[lane + 64] * a[lane + 64];
        #pragma unroll
        for (int m = 32; m; m >>= 1) p += __shfl_xor(p, m);
        if (lane == 0) wd[idx] = p;
    }
}

// Wt[l][c][k] = Wg[l][k][c] as fp16  (for MFMA B-operand contiguous-k loads)
__global__ void k_wprep(const float* __restrict__ Wg, __half* __restrict__ Wt) {
    int i = blockIdx.x * 256 + threadIdx.x;   // l*32768 + c*128 + k
    if (i >= 3 * 256 * 128) return;
    int l = i >> 15, rem = i & 32767;
    int c = rem >> 7, kk = rem & 127;
    Wt[i] = __float2half_rn(Wg[l * 32768 + kk * 256 + c]);
}

// ---------------- embed: h = x @ W_emb  (N,56)@(56,128), fp32 + fp16 out ----------------
__global__ __launch_bounds__(128) void k_embed(const float* __restrict__ x, const float* __restrict__ W,
                                               float* __restrict__ h, __half* __restrict__ h16) {
    __shared__ float xs[FINN];
    int n = blockIdx.x, t = threadIdx.x;
    if (t < FINN) xs[t] = x[n * FINN + t];
    __syncthreads();
    float acc = 0.f;
    #pragma unroll
    for (int f = 0; f < FINN; ++f) acc += xs[f] * W[f * CC + t];
    h[n * CC + t] = acc;
    h16[n * CC + t] = __float2half_rn(acc);
}

// ---------------- MFMA GEMM: hh16 = h16 @ Wt^T, fused ls/ld ----------------
// block: 256 thr (4 waves), 16 rows; wave w covers cols [64w, 64w+64), head = w>>1
// lsld[n*4] = {ls0, ls1, ld0, ld1}
__global__ __launch_bounds__(256) void k_gemm16(
    const __half* __restrict__ h16, const __half* __restrict__ Wt,
    const float* __restrict__ as_, const float* __restrict__ ad_,
    __half* __restrict__ hh16, float* __restrict__ lsld) {
    __shared__ float2 red[16][4];
    int tid = threadIdx.x;
    int wave = tid >> 6, lane = tid & 63;
    int row0 = blockIdx.x * 16;
    int rlo = lane & 15, kgrp = lane >> 4;
    // A fragments: A[row = rlo][k = kgrp*8 + j], 4 K-steps of 32
    f16x8 afrag[4];
    const __half* abase = h16 + (row0 + rlo) * CC + kgrp * 8;
    #pragma unroll
    for (int ks = 0; ks < 4; ++ks) afrag[ks] = *(const f16x8*)(abase + ks * 32);
    int head = wave >> 1;
    const float* as_h = as_ + head * CC;
    const float* ad_h = ad_ + head * CC;
    float psum[4] = {0.f, 0.f, 0.f, 0.f}, pdsum[4] = {0.f, 0.f, 0.f, 0.f};
    #pragma unroll
    for (int nt = 0; nt < 4; ++nt) {
        int col = wave * 64 + nt * 16 + rlo;
        f32x4 acc = {0.f, 0.f, 0.f, 0.f};
        const __half* bbase = Wt + col * CC + kgrp * 8;
        #pragma unroll
        for (int ks = 0; ks < 4; ++ks) {
            f16x8 bfrag = *(const f16x8*)(bbase + ks * 32);
            acc = __builtin_amdgcn_mfma_f32_16x16x32_f16(afrag[ks], bfrag, acc, 0, 0, 0);
        }
        float av = as_h[col & 127], dv = ad_h[col & 127];
        #pragma unroll
        for (int r = 0; r < 4; ++r) {
            float v = acc[r];
            hh16[(row0 + kgrp * 4 + r) * 256 + col] = __float2half_rn(v);
            psum[r] += v * av;
            pdsum[r] += v * dv;
        }
    }
    // reduce over the 16 cols within this lane-group (masks 1,2,4,8 stay in-group)
    #pragma unroll
    for (int r = 0; r < 4; ++r) {
        #pragma unroll
        for (int m = 1; m < 16; m <<= 1) {
            psum[r] += __shfl_xor(psum[r], m);
            pdsum[r] += __shfl_xor(pdsum[r], m);
        }
    }
    if (rlo == 0) {
        #pragma unroll
        for (int r = 0; r < 4; ++r) red[kgrp * 4 + r][wave] = make_float2(psum[r], pdsum[r]);
    }
    __syncthreads();
    if (tid < 64) {
        int row = tid >> 2, which = tid & 3;
        float v;
        if (which == 0)      v = red[row][0].x + red[row][1].x;  // ls0
        else if (which == 1) v = red[row][2].x + red[row][3].x;  // ls1
        else if (which == 2) v = red[row][0].y + red[row][1].y;  // ld0
        else                 v = red[row][2].y + red[row][3].y;  // ld1
        lsld[(row0 + row) * 4 + which] = v;
    }
}

// ---------------- fused attention (both gates), fp16 gather, 2 edges/iter ----------------
__global__ __launch_bounds__(256) void k_attn(
    const __half* __restrict__ hh16, const float* __restrict__ hcur,
    const float* __restrict__ lsld,
    const int* __restrict__ row_ptr, const int4* __restrict__ csr,
    const float* __restrict__ wd, const float* __restrict__ bg,
    const float* __restrict__ gw, const float* __restrict__ gb,
    float* __restrict__ hout, __half* __restrict__ h16out) {
    __shared__ float4 evM[4][64];     // {e00,e01,e10,e11} per edge — contiguous, conflict-free
    __shared__ int    evS[4][64];     // src byte offset (src * 512)
    int wid = threadIdx.x >> 6, lane = threadIdx.x & 63;
    int n = blockIdx.x * 4 + wid;       // NN % 4 == 0
    float wd0 = wd[0], wd1 = wd[1];
    float4 nld = *(const float4*)&lsld[n * 4];
    float ld0 = nld.z, ld1 = nld.w;
    int jbeg = __builtin_amdgcn_readfirstlane(row_ptr[n]);
    int jend = __builtin_amdgcn_readfirstlane(row_ptr[n + 1]);
    int grp  = lane >> 5;               // which edge of the pair
    int sub  = lane & 31;               // channel group: 8 ch at sub*8
    int hd01 = sub >> 4;                // head for my channels
    float s0 = 0, s1 = 0, s2 = 0, s3 = 0;
    float acc1[8] = {0,0,0,0,0,0,0,0}, acc2[8] = {0,0,0,0,0,0,0,0};
    const char* hbase = (const char*)hh16 + sub * 16;

    for (int j0 = jbeg; j0 < jend; j0 += 64) {
        int j = j0 + lane;
        int nact = min(64, jend - j0);
        float4 e4 = make_float4(0.f, 0.f, 0.f, 0.f);
        int smine = 0;
        if (j < jend) {
            int4 c = csr[j];
            smine = c.x;
            float a1 = __int_as_float(c.y), a2 = __int_as_float(c.z);
            float2 lsv = *(const float2*)&lsld[smine * 4];
            float b0 = lsv.x + ld0, b1 = lsv.y + ld1;
            e4.x = __expf(fminf(lrelu(b0 + a1 * wd0), 80.f));
            e4.y = __expf(fminf(lrelu(b0 + a2 * wd0), 80.f));
            e4.z = __expf(fminf(lrelu(b1 + a1 * wd1), 80.f));
            e4.w = __expf(fminf(lrelu(b1 + a2 * wd1), 80.f));
            s0 += e4.x; s1 += e4.y; s2 += e4.z; s3 += e4.w;
        }
        evM[wid][lane] = e4;
        evS[wid][lane] = smine * 512;
        int it = (nact + 1) >> 1;
        #pragma unroll 2
        for (int jj = 0; jj < it; ++jj) {
            int ed = 2 * jj + grp;
            float4 em = evM[wid][ed];         // broadcast within 32-lane group
            int off = evS[wid][ed];
            float e1 = hd01 ? em.z : em.x;
            float e2 = hd01 ? em.w : em.y;
            uint4 raw = *(const uint4*)(hbase + off);
            float2 f0 = __half22float2(*(__half2*)&raw.x);
            float2 f1 = __half22float2(*(__half2*)&raw.y);
            float2 f2 = __half22float2(*(__half2*)&raw.z);
            float2 f3 = __half22float2(*(__half2*)&raw.w);
            acc1[0] += e1 * f0.x; acc1[1] += e1 * f0.y;
            acc1[2] += e1 * f1.x; acc1[3] += e1 * f1.y;
            acc1[4] += e1 * f2.x; acc1[5] += e1 * f2.y;
            acc1[6] += e1 * f3.x; acc1[7] += e1 * f3.y;
            acc2[0] += e2 * f0.x; acc2[1] += e2 * f0.y;
            acc2[2] += e2 * f1.x; acc2[3] += e2 * f1.y;
            acc2[4] += e2 * f2.x; acc2[5] += e2 * f2.y;
            acc2[6] += e2 * f3.x; acc2[7] += e2 * f3.y;
        }
    }
    // combine the two edge-groups (lane l and l^32 hold same channels)
    #pragma unroll
    for (int i = 0; i < 8; ++i) {
        acc1[i] += __shfl_xor(acc1[i], 32);
        acc2[i] += __shfl_xor(acc2[i], 32);
    }
    #pragma unroll
    for (int m = 32; m; m >>= 1) {
        s0 += __shfl_xor(s0, m); s1 += __shfl_xor(s1, m);
        s2 += __shfl_xor(s2, m); s3 += __shfl_xor(s3, m);
    }
    float d1 = (hd01 ? s2 : s0) + 1e-16f;
    float d2 = (hd01 ? s3 : s1) + 1e-16f;
    int c0 = (sub & 15) * 8;            // within-head channel base (also output channel base)
    float o1[8], o2[8];
    #pragma unroll
    for (int i = 0; i < 8; ++i) { o1[i] = acc1[i] / d1; o2[i] = acc2[i] / d2; }
    // head-mean: partner lane sub^16 holds the other head's same within-head channels
    #pragma unroll
    for (int i = 0; i < 8; ++i) {
        o1[i] = 0.5f * (o1[i] + __shfl_xor(o1[i], 16)) + bg[c0 + i];
        o2[i] = 0.5f * (o2[i] + __shfl_xor(o2[i], 16)) + bg[c0 + i];
    }
    float hv[8];
    *(float4*)&hv[0] = ((const float4*)hcur)[n * 32 + (sub & 15) * 2];
    *(float4*)&hv[4] = ((const float4*)hcur)[n * 32 + (sub & 15) * 2 + 1];
    float pp1 = 0.f, pp2 = 0.f;
    if (lane < 16) {
        #pragma unroll
        for (int i = 0; i < 8; ++i) {
            pp1 += o1[i] * gw[128 + c0 + i];
            pp2 += o2[i] * gw[128 + c0 + i];
        }
    } else if (lane < 32) {
        float hp = 0.f;
        #pragma unroll
        for (int i = 0; i < 8; ++i) hp += hv[i] * gw[c0 + i];
        pp1 = hp; pp2 = hp;
    }
    #pragma unroll
    for (int m = 32; m; m >>= 1) { pp1 += __shfl_xor(pp1, m); pp2 += __shfl_xor(pp2, m); }
    float z1 = 1.f / (1.f + __expf(-(pp1 + gb[0])));
    float z2 = 1.f / (1.f + __expf(-(pp2 + gb[0])));
    if (lane < 16) {
        float r[8];
        #pragma unroll
        for (int i = 0; i < 8; ++i) {
            float g1 = z1 * hv[i] + (1.f - z1) * fmaxf(o1[i], 0.f);
            float g2 = z2 * hv[i] + (1.f - z2) * fmaxf(o2[i], 0.f);
            r[i] = g2 - g1;
        }
        ((float4*)hout)[n * 32 + (sub & 15) * 2]     = make_float4(r[0], r[1], r[2], r[3]);
        ((float4*)hout)[n * 32 + (sub & 15) * 2 + 1] = make_float4(r[4], r[5], r[6], r[7]);
        union { __half h[8]; uint4 u; } pk;
        #pragma unroll
        for (int i = 0; i < 8; ++i) pk.h[i] = __float2half_rn(r[i]);
        *(uint4*)&h16out[n * CC + c0] = pk.u;
    }
}

// ---------------- readout: segment sums over sorted batch_idx ----------------
__global__ __launch_bounds__(128) void k_readout(const float* __restrict__ h, const float* __restrict__ valid,
                                                 const int* __restrict__ batch, float* __restrict__ obuf) {
    int g = blockIdx.x, t = threadIdx.x;
    int lo = 0, hi = NN;
    while (lo < hi) { int mid = (lo + hi) >> 1; if (batch[mid] < g) lo = mid + 1; else hi = mid; }
    int s = lo;
    lo = s; hi = NN;
    while (lo < hi) { int mid = (lo + hi) >> 1; if (batch[mid] < g + 1) lo = mid + 1; else hi = mid; }
    int e = lo;
    float gl = 0, gp = 0;
    for (int n = s; n < e; ++n) {
        float hv = h[n * CC + t];
        gl += hv * valid[n * 2];
        gp += hv * valid[n * 2 + 1];
    }
    obuf[g * 256 + t] = gl;
    obuf[g * 256 + 128 + t] = gp;
}

// ---------------- per-graph MLP ----------------
__global__ __launch_bounds__(128) void k_mlp(const float* __restrict__ obuf,
    const float* __restrict__ w0, const float* __restrict__ b0,
    const float* __restrict__ w1, const float* __restrict__ b1,
    const float* __restrict__ w2, const float* __restrict__ b2,
    const float* __restrict__ w3, const float* __restrict__ b3,
    float* __restrict__ out) {
    __shared__ float cur[256];
    __shared__ float nxt[128];
    int g = blockIdx.x, t = threadIdx.x;
    cur[t] = obuf[g * 256 + t];
    cur[t + 128] = obuf[g * 256 + 128 + t];
    __syncthreads();
    float s = b0[t];
    for (int i = 0; i < 256; ++i) s += cur[i] * w0[i * 128 + t];
    nxt[t] = fmaxf(s, 0.f);
    __syncthreads();
    s = b1[t];
    for (int i = 0; i < 128; ++i) s += nxt[i] * w1[i * 128 + t];
    cur[t] = fmaxf(s, 0.f);
    __syncthreads();
    s = b2[t];
    for (int i = 0; i < 128; ++i) s += cur[i] * w2[i * 128 + t];
    nxt[t] = fmaxf(s, 0.f);
    __syncthreads();
    if (t < 2) {
        float o = b3[t];
        for (int i = 0; i < 128; ++i) o += nxt[i] * w3[i * 2 + t];
        out[g * 2 + t] = (t == 1) ? expf(o) : o;
    }
}

extern "C" void kernel_launch(void* const* d_in, const int* in_sizes, int n_in,
                              void* d_out, int out_size, void* d_ws, size_t ws_size,
                              hipStream_t stream) {
    const float* x      = (const float*)d_in[0];
    const int*   ei     = (const int*)d_in[1];
    const float* ea     = (const float*)d_in[2];
    const float* valid  = (const float*)d_in[3];
    const int*   batch  = (const int*)d_in[4];
    const float* mu     = (const float*)d_in[5];
    const float* devp   = (const float*)d_in[6];
    const float* W_emb  = (const float*)d_in[7];
    const float* Wg     = (const float*)d_in[8];
    const float* att_s  = (const float*)d_in[9];
    const float* att_d  = (const float*)d_in[10];
    const float* We     = (const float*)d_in[11];
    const float* att_e  = (const float*)d_in[12];
    const float* bg     = (const float*)d_in[13];
    const float* gw     = (const float*)d_in[14];
    const float* gb     = (const float*)d_in[15];
    const float* fw0    = (const float*)d_in[16];
    const float* fb0    = (const float*)d_in[17];
    const float* fw1    = (const float*)d_in[18];
    const float* fb1    = (const float*)d_in[19];
    const float* fw2    = (const float*)d_in[20];
    const float* fb2    = (const float*)d_in[21];
    const float* fw3    = (const float*)d_in[22];
    const float* fb3    = (const float*)d_in[23];
    float* out = (float*)d_out;

    char* p = (char*)d_ws;
    auto alloc = [&](size_t bytes) -> char* {
        char* r = p;
        p += (bytes + 255) & ~(size_t)255;
        return r;
    };
    float*  h0      = (float*)alloc((size_t)NN * CC * 4);
    float*  h1      = (float*)alloc((size_t)NN * CC * 4);
    __half* h16a    = (__half*)alloc((size_t)NN * CC * 2);
    __half* h16b    = (__half*)alloc((size_t)NN * CC * 2);
    __half* hh16    = (__half*)alloc((size_t)NN * 256 * 2);
    __half* Wt      = (__half*)alloc((size_t)3 * 256 * 128 * 2);
    float*  lsld    = (float*)alloc((size_t)NN * 4 * 4);
    int*    deg     = (int*)alloc((size_t)NN * 4);
    int*    row_ptr = (int*)alloc((size_t)(NN + 1) * 4);
    int*    cursor  = (int*)alloc((size_t)NN * 4);
    int*    bsum    = (int*)alloc(1024);
    int4*   csr     = (int4*)alloc((size_t)EE * 16);
    float*  wd      = (float*)alloc(256);
    float*  obuf    = (float*)alloc((size_t)GG * 256 * 4);

    const int NB = (NN + 255) / 256;  // 157

    // CSR by dst
    hipMemsetAsync(deg, 0, (size_t)NN * 4, stream);
    k_hist<<<(EE + 255) / 256, 256, 0, stream>>>(ei + EE, deg);
    k_scanA<<<NB, 256, 0, stream>>>(deg, row_ptr + 1, bsum);
    k_scanB<<<1, 256, 0, stream>>>(bsum, NB);
    k_scanC<<<NB, 256, 0, stream>>>(row_ptr, bsum);
    k_copycur<<<NB, 256, 0, stream>>>(row_ptr, cursor);
    k_scatter<<<(EE + 255) / 256, 256, 0, stream>>>(ei, ea, mu, devp, cursor, csr);
    k_wedot<<<1, 64, 0, stream>>>(We, att_e, wd);
    k_wprep<<<(3 * 256 * 128 + 255) / 256, 256, 0, stream>>>(Wg, Wt);

    // embed
    k_embed<<<NN, 128, 0, stream>>>(x, W_emb, h0, h16a);

    float*  hc = h0;   float*  hn = h1;
    __half* hc16 = h16a; __half* hn16 = h16b;
    for (int k = 0; k < 3; ++k) {
        k_gemm16<<<NN / 16, 256, 0, stream>>>(hc16, Wt + (size_t)k * 32768,
                                              att_s + k * 256, att_d + k * 256, hh16, lsld);
        k_attn<<<NN / 4, 256, 0, stream>>>(hh16, hc, lsld, row_ptr, csr,
                                           wd + k * 2, bg + k * 128, gw + k * 256, gb + k,
                                           hn, hn16);
        float* t1 = hc; hc = hn; hn = t1;
        __half* t2 = hc16; hc16 = hn16; hn16 = t2;
    }

    k_readout<<<GG, 128, 0, stream>>>(hc, valid, batch, obuf);
    k_mlp<<<GG, 128, 0, stream>>>(obuf, fw0, fb0, fw1, fb1, fw2, fb2, fw3, fb3, out);
}

// Round 7
// 443.425 us; speedup vs baseline: 1.4344x; 1.1238x over previous
//
#include <hip/hip_runtime.h>
#include <hip/hip_fp16.h>
#include <math.h>

#define NN 40000
#define EE 500000
#define CC 128
#define GG 800
#define FINN 56
#define NEGS 0.2f

typedef _Float16 f16x8 __attribute__((ext_vector_type(8)));
typedef float f32x4 __attribute__((ext_vector_type(4)));

__device__ __forceinline__ float lrelu(float x) { return x > 0.f ? x : NEGS * x; }

// ---------------- CSR build ----------------
__global__ void k_hist(const int* __restrict__ dst, int* __restrict__ deg) {
    int e = blockIdx.x * 256 + threadIdx.x;
    if (e < EE) atomicAdd(&deg[dst[e]], 1);
}

__global__ void k_scanA(const int* __restrict__ deg, int* __restrict__ row1, int* __restrict__ bsum) {
    __shared__ int buf[256];
    int i = blockIdx.x * 256 + threadIdx.x;
    int v = (i < NN) ? deg[i] : 0;
    buf[threadIdx.x] = v;
    __syncthreads();
    for (int off = 1; off < 256; off <<= 1) {
        int t = (threadIdx.x >= off) ? buf[threadIdx.x - off] : 0;
        __syncthreads();
        buf[threadIdx.x] += t;
        __syncthreads();
    }
    if (i < NN) row1[i] = buf[threadIdx.x];
    if (threadIdx.x == 255) bsum[blockIdx.x] = buf[255];
}

__global__ void k_scanB(int* bsum, int nb) {
    __shared__ int buf[256];
    int v = (threadIdx.x < nb) ? bsum[threadIdx.x] : 0;
    buf[threadIdx.x] = v;
    __syncthreads();
    for (int off = 1; off < 256; off <<= 1) {
        int t = (threadIdx.x >= off) ? buf[threadIdx.x - off] : 0;
        __syncthreads();
        buf[threadIdx.x] += t;
        __syncthreads();
    }
    if (threadIdx.x < nb) bsum[threadIdx.x] = buf[threadIdx.x] - v;  // exclusive
}

// finalize row_ptr and derive cursor (fused old scanC + copycur)
__global__ void k_scanC2(int* __restrict__ row_ptr, const int* __restrict__ bsum,
                         const int* __restrict__ deg, int* __restrict__ cursor) {
    int i = blockIdx.x * 256 + threadIdx.x;
    if (i < NN) {
        int v = row_ptr[i + 1] + bsum[blockIdx.x];
        row_ptr[i + 1] = v;
        cursor[i] = v - deg[i];
    }
    if (i == 0) row_ptr[0] = 0;
}

// interleaved CSR record: {src, a1 bits, a2 bits, pad}
__global__ void k_scatter(const int* __restrict__ ei, const float* __restrict__ ea,
                          const float* __restrict__ mu, const float* __restrict__ dev,
                          int* __restrict__ cursor, int4* __restrict__ csr) {
    int e = blockIdx.x * 256 + threadIdx.x;
    if (e >= EE) return;
    int s = ei[e], d = ei[EE + e];
    float a1 = ea[2 * e];
    float xx = ea[2 * e + 1] - mu[0];
    float a2 = __expf(-xx * xx / dev[0]) + a1;
    int p = atomicAdd(&cursor[d], 1);
    csr[p] = make_int4(s, __float_as_int(a1), __float_as_int(a2), 0);
}

// we_dot[k*2+h] = sum_c We[k,0,h*128+c] * att_e[k,h,c]
__global__ void k_wedot(const float* __restrict__ We, const float* __restrict__ ate, float* __restrict__ wd) {
    int lane = threadIdx.x;  // 64
    for (int idx = 0; idx < 6; ++idx) {
        const float* w = We + idx * 128;
        const float* a = ate + idx * 128;
        float p = w[lane] * a[lane] + w[lane + 64] * a[lane + 64];
        #pragma unroll
        for (int m = 32; m; m >>= 1) p += __shfl_xor(p, m);
        if (lane == 0) wd[idx] = p;
    }
}

// combined prep: x16 pad-convert, Wt (Wg transpose fp16), Wet (W_emb transpose fp16, K padded to 64)
#define XS (NN * 64)
#define WGSZ (3 * 256 * 128)
#define WESZ (128 * 64)
__global__ void k_prep(const float* __restrict__ x, const float* __restrict__ Wg,
                       const float* __restrict__ W_emb,
                       __half* __restrict__ x16, __half* __restrict__ Wt, __half* __restrict__ Wet) {
    int i = blockIdx.x * 256 + threadIdx.x;
    if (i < XS) {
        int n = i >> 6, k = i & 63;
        x16[i] = (k < FINN) ? __float2half_rn(x[n * FINN + k]) : __half(0.f);
    } else if (i < XS + WGSZ) {
        int j = i - XS;                 // l*32768 + c*128 + k
        int l = j >> 15, rem = j & 32767;
        int c = rem >> 7, kk = rem & 127;
        Wt[j] = __float2half_rn(Wg[l * 32768 + kk * 256 + c]);
    } else if (i < XS + WGSZ + WESZ) {
        int j = i - XS - WGSZ;          // c*64 + k
        int c = j >> 6, kk = j & 63;
        Wet[j] = (kk < FINN) ? __float2half_rn(W_emb[kk * CC + c]) : __half(0.f);
    }
}

// ---------------- embed via MFMA: h = x16 @ Wet^T (K=64), fp32 + fp16 out ----------------
__global__ __launch_bounds__(128) void k_embed16(
    const __half* __restrict__ x16, const __half* __restrict__ Wet,
    float* __restrict__ h, __half* __restrict__ h16) {
    int tid = threadIdx.x;
    int wave = tid >> 6, lane = tid & 63;
    int row0 = blockIdx.x * 16;
    int rlo = lane & 15, kgrp = lane >> 4;
    const __half* abase = x16 + (row0 + rlo) * 64 + kgrp * 8;
    f16x8 a0 = *(const f16x8*)(abase);
    f16x8 a1 = *(const f16x8*)(abase + 32);
    #pragma unroll
    for (int nt = 0; nt < 4; ++nt) {
        int col = wave * 64 + nt * 16 + rlo;
        f32x4 acc = {0.f, 0.f, 0.f, 0.f};
        const __half* bbase = Wet + col * 64 + kgrp * 8;
        acc = __builtin_amdgcn_mfma_f32_16x16x32_f16(a0, *(const f16x8*)(bbase), acc, 0, 0, 0);
        acc = __builtin_amdgcn_mfma_f32_16x16x32_f16(a1, *(const f16x8*)(bbase + 32), acc, 0, 0, 0);
        #pragma unroll
        for (int r = 0; r < 4; ++r) {
            int row = row0 + kgrp * 4 + r;
            h[row * CC + col] = acc[r];
            h16[row * CC + col] = __float2half_rn(acc[r]);
        }
    }
}

// ---------------- MFMA GEMM: hh16 = h16 @ Wt^T, fused ls/ld ----------------
__global__ __launch_bounds__(256) void k_gemm16(
    const __half* __restrict__ h16, const __half* __restrict__ Wt,
    const float* __restrict__ as_, const float* __restrict__ ad_,
    __half* __restrict__ hh16, float* __restrict__ lsld) {
    __shared__ float2 red[16][4];
    int tid = threadIdx.x;
    int wave = tid >> 6, lane = tid & 63;
    int row0 = blockIdx.x * 16;
    int rlo = lane & 15, kgrp = lane >> 4;
    f16x8 afrag[4];
    const __half* abase = h16 + (row0 + rlo) * CC + kgrp * 8;
    #pragma unroll
    for (int ks = 0; ks < 4; ++ks) afrag[ks] = *(const f16x8*)(abase + ks * 32);
    int head = wave >> 1;
    const float* as_h = as_ + head * CC;
    const float* ad_h = ad_ + head * CC;
    float psum[4] = {0.f, 0.f, 0.f, 0.f}, pdsum[4] = {0.f, 0.f, 0.f, 0.f};
    #pragma unroll
    for (int nt = 0; nt < 4; ++nt) {
        int col = wave * 64 + nt * 16 + rlo;
        f32x4 acc = {0.f, 0.f, 0.f, 0.f};
        const __half* bbase = Wt + col * CC + kgrp * 8;
        #pragma unroll
        for (int ks = 0; ks < 4; ++ks) {
            f16x8 bfrag = *(const f16x8*)(bbase + ks * 32);
            acc = __builtin_amdgcn_mfma_f32_16x16x32_f16(afrag[ks], bfrag, acc, 0, 0, 0);
        }
        float av = as_h[col & 127], dv = ad_h[col & 127];
        #pragma unroll
        for (int r = 0; r < 4; ++r) {
            float v = acc[r];
            hh16[(row0 + kgrp * 4 + r) * 256 + col] = __float2half_rn(v);
            psum[r] += v * av;
            pdsum[r] += v * dv;
        }
    }
    #pragma unroll
    for (int r = 0; r < 4; ++r) {
        #pragma unroll
        for (int m = 1; m < 16; m <<= 1) {
            psum[r] += __shfl_xor(psum[r], m);
            pdsum[r] += __shfl_xor(pdsum[r], m);
        }
    }
    if (rlo == 0) {
        #pragma unroll
        for (int r = 0; r < 4; ++r) red[kgrp * 4 + r][wave] = make_float2(psum[r], pdsum[r]);
    }
    __syncthreads();
    if (tid < 64) {
        int row = tid >> 2, which = tid & 3;
        float v;
        if (which == 0)      v = red[row][0].x + red[row][1].x;  // ls0
        else if (which == 1) v = red[row][2].x + red[row][3].x;  // ls1
        else if (which == 2) v = red[row][0].y + red[row][1].y;  // ld0
        else                 v = red[row][2].y + red[row][3].y;  // ld1
        lsld[(row0 + row) * 4 + which] = v;
    }
}

// ---------------- fused attention: one node per 32-lane half-wave ----------------
__global__ __launch_bounds__(256) void k_attn(
    const __half* __restrict__ hh16, const float* __restrict__ hcur,
    const float* __restrict__ lsld,
    const int* __restrict__ row_ptr, const int4* __restrict__ csr,
    const float* __restrict__ wd, const float* __restrict__ bg,
    const float* __restrict__ gw, const float* __restrict__ gb,
    float* __restrict__ hout, __half* __restrict__ h16out) {
    __shared__ float4 evM[8][32];     // per half-wave edge coeffs {e00,e01,e10,e11}
    __shared__ int    evS[8][32];     // src byte offsets (src*512)
    int tid = threadIdx.x;
    int sub = tid & 31;
    int hw = tid >> 5;                // half-wave 0..7
    int n = blockIdx.x * 8 + hw;      // NN % 8 == 0
    float wd0 = wd[0], wd1 = wd[1];
    float4 nld = *(const float4*)&lsld[n * 4];
    float ld0 = nld.z, ld1 = nld.w;
    int jbeg = row_ptr[n], jend = row_ptr[n + 1];
    int hd01 = sub >> 4;              // head for my 8 channels
    float s0 = 0, s1 = 0, s2 = 0, s3 = 0;
    float acc1[8] = {0,0,0,0,0,0,0,0}, acc2[8] = {0,0,0,0,0,0,0,0};
    const char* hbase = (const char*)hh16 + sub * 16;

    for (int j0 = jbeg; j0 < jend; j0 += 32) {
        int j = j0 + sub;
        int nact = min(32, jend - j0);
        float4 e4 = make_float4(0.f, 0.f, 0.f, 0.f);
        int smine = 0;
        if (j < jend) {
            int4 c = csr[j];
            smine = c.x;
            float a1 = __int_as_float(c.y), a2 = __int_as_float(c.z);
            float2 lsv = *(const float2*)&lsld[smine * 4];
            float b0 = lsv.x + ld0, b1 = lsv.y + ld1;
            e4.x = __expf(fminf(lrelu(b0 + a1 * wd0), 80.f));
            e4.y = __expf(fminf(lrelu(b0 + a2 * wd0), 80.f));
            e4.z = __expf(fminf(lrelu(b1 + a1 * wd1), 80.f));
            e4.w = __expf(fminf(lrelu(b1 + a2 * wd1), 80.f));
            s0 += e4.x; s1 += e4.y; s2 += e4.z; s3 += e4.w;
        }
        evM[hw][sub] = e4;
        evS[hw][sub] = smine * 512;
        #pragma unroll 2
        for (int jj = 0; jj < nact; ++jj) {
            float4 em = evM[hw][jj];          // broadcast within half-wave
            int off = evS[hw][jj];
            float e1 = hd01 ? em.z : em.x;
            float e2 = hd01 ? em.w : em.y;
            union { uint4 u; _Float16 hx[8]; } cv;
            cv.u = *(const uint4*)(hbase + off);
            #pragma unroll
            for (int i = 0; i < 8; ++i) {
                float v = (float)cv.hx[i];    // fma_mix candidate
                acc1[i] += e1 * v;
                acc2[i] += e2 * v;
            }
        }
    }
    #pragma unroll
    for (int m = 16; m; m >>= 1) {
        s0 += __shfl_xor(s0, m); s1 += __shfl_xor(s1, m);
        s2 += __shfl_xor(s2, m); s3 += __shfl_xor(s3, m);
    }
    float d1 = (hd01 ? s2 : s0) + 1e-16f;
    float d2 = (hd01 ? s3 : s1) + 1e-16f;
    float id1 = 1.f / d1, id2 = 1.f / d2;
    int c0 = (sub & 15) * 8;              // within-head / output channel base
    float o1[8], o2[8];
    #pragma unroll
    for (int i = 0; i < 8; ++i) { o1[i] = acc1[i] * id1; o2[i] = acc2[i] * id2; }
    // head-mean: partner lane sub^16 holds the other head's same channels
    #pragma unroll
    for (int i = 0; i < 8; ++i) {
        o1[i] = 0.5f * (o1[i] + __shfl_xor(o1[i], 16)) + bg[c0 + i];
        o2[i] = 0.5f * (o2[i] + __shfl_xor(o2[i], 16)) + bg[c0 + i];
    }
    float hv[8];
    *(float4*)&hv[0] = ((const float4*)hcur)[n * 32 + (sub & 15) * 2];
    *(float4*)&hv[4] = ((const float4*)hcur)[n * 32 + (sub & 15) * 2 + 1];
    float pp1 = 0.f, pp2 = 0.f;
    if (sub < 16) {
        #pragma unroll
        for (int i = 0; i < 8; ++i) {
            pp1 += o1[i] * gw[128 + c0 + i];
            pp2 += o2[i] * gw[128 + c0 + i];
        }
    } else {
        float hp = 0.f;
        #pragma unroll
        for (int i = 0; i < 8; ++i) hp += hv[i] * gw[c0 + i];
        pp1 = hp; pp2 = hp;
    }
    #pragma unroll
    for (int m = 16; m; m >>= 1) { pp1 += __shfl_xor(pp1, m); pp2 += __shfl_xor(pp2, m); }
    float z1 = 1.f / (1.f + __expf(-(pp1 + gb[0])));
    float z2 = 1.f / (1.f + __expf(-(pp2 + gb[0])));
    if (sub < 16) {
        float r[8];
        #pragma unroll
        for (int i = 0; i < 8; ++i) {
            float g1 = z1 * hv[i] + (1.f - z1) * fmaxf(o1[i], 0.f);
            float g2 = z2 * hv[i] + (1.f - z2) * fmaxf(o2[i], 0.f);
            r[i] = g2 - g1;
        }
        ((float4*)hout)[n * 32 + (sub & 15) * 2]     = make_float4(r[0], r[1], r[2], r[3]);
        ((float4*)hout)[n * 32 + (sub & 15) * 2 + 1] = make_float4(r[4], r[5], r[6], r[7]);
        union { __half h[8]; uint4 u; } pk;
        #pragma unroll
        for (int i = 0; i < 8; ++i) pk.h[i] = __float2half_rn(r[i]);
        *(uint4*)&h16out[n * CC + c0] = pk.u;
    }
}

// ---------------- readout: segment sums over sorted batch_idx ----------------
__global__ __launch_bounds__(128) void k_readout(const float* __restrict__ h, const float* __restrict__ valid,
                                                 const int* __restrict__ batch, float* __restrict__ obuf) {
    int g = blockIdx.x, t = threadIdx.x;
    int lo = 0, hi = NN;
    while (lo < hi) { int mid = (lo + hi) >> 1; if (batch[mid] < g) lo = mid + 1; else hi = mid; }
    int s = lo;
    lo = s; hi = NN;
    while (lo < hi) { int mid = (lo + hi) >> 1; if (batch[mid] < g + 1) lo = mid + 1; else hi = mid; }
    int e = lo;
    float gl = 0, gp = 0;
    for (int n = s; n < e; ++n) {
        float hv = h[n * CC + t];
        gl += hv * valid[n * 2];
        gp += hv * valid[n * 2 + 1];
    }
    obuf[g * 256 + t] = gl;
    obuf[g * 256 + 128 + t] = gp;
}

// ---------------- per-graph MLP ----------------
__global__ __launch_bounds__(128) void k_mlp(const float* __restrict__ obuf,
    const float* __restrict__ w0, const float* __restrict__ b0,
    const float* __restrict__ w1, const float* __restrict__ b1,
    const float* __restrict__ w2, const float* __restrict__ b2,
    const float* __restrict__ w3, const float* __restrict__ b3,
    float* __restrict__ out) {
    __shared__ float cur[256];
    __shared__ float nxt[128];
    int g = blockIdx.x, t = threadIdx.x;
    cur[t] = obuf[g * 256 + t];
    cur[t + 128] = obuf[g * 256 + 128 + t];
    __syncthreads();
    float s = b0[t];
    for (int i = 0; i < 256; ++i) s += cur[i] * w0[i * 128 + t];
    nxt[t] = fmaxf(s, 0.f);
    __syncthreads();
    s = b1[t];
    for (int i = 0; i < 128; ++i) s += nxt[i] * w1[i * 128 + t];
    cur[t] = fmaxf(s, 0.f);
    __syncthreads();
    s = b2[t];
    for (int i = 0; i < 128; ++i) s += cur[i] * w2[i * 128 + t];
    nxt[t] = fmaxf(s, 0.f);
    __syncthreads();
    if (t < 2) {
        float o = b3[t];
        for (int i = 0; i < 128; ++i) o += nxt[i] * w3[i * 2 + t];
        out[g * 2 + t] = (t == 1) ? expf(o) : o;
    }
}

extern "C" void kernel_launch(void* const* d_in, const int* in_sizes, int n_in,
                              void* d_out, int out_size, void* d_ws, size_t ws_size,
                              hipStream_t stream) {
    const float* x      = (const float*)d_in[0];
    const int*   ei     = (const int*)d_in[1];
    const float* ea     = (const float*)d_in[2];
    const float* valid  = (const float*)d_in[3];
    const int*   batch  = (const int*)d_in[4];
    const float* mu     = (const float*)d_in[5];
    const float* devp   = (const float*)d_in[6];
    const float* W_emb  = (const float*)d_in[7];
    const float* Wg     = (const float*)d_in[8];
    const float* att_s  = (const float*)d_in[9];
    const float* att_d  = (const float*)d_in[10];
    const float* We     = (const float*)d_in[11];
    const float* att_e  = (const float*)d_in[12];
    const float* bg     = (const float*)d_in[13];
    const float* gw     = (const float*)d_in[14];
    const float* gb     = (const float*)d_in[15];
    const float* fw0    = (const float*)d_in[16];
    const float* fb0    = (const float*)d_in[17];
    const float* fw1    = (const float*)d_in[18];
    const float* fb1    = (const float*)d_in[19];
    const float* fw2    = (const float*)d_in[20];
    const float* fb2    = (const float*)d_in[21];
    const float* fw3    = (const float*)d_in[22];
    const float* fb3    = (const float*)d_in[23];
    float* out = (float*)d_out;

    char* p = (char*)d_ws;
    auto alloc = [&](size_t bytes) -> char* {
        char* r = p;
        p += (bytes + 255) & ~(size_t)255;
        return r;
    };
    float*  h0      = (float*)alloc((size_t)NN * CC * 4);
    float*  h1      = (float*)alloc((size_t)NN * CC * 4);
    __half* h16a    = (__half*)alloc((size_t)NN * CC * 2);
    __half* h16b    = (__half*)alloc((size_t)NN * CC * 2);
    __half* hh16    = (__half*)alloc((size_t)NN * 256 * 2);
    __half* x16     = (__half*)alloc((size_t)NN * 64 * 2);
    __half* Wt      = (__half*)alloc((size_t)3 * 256 * 128 * 2);
    __half* Wet     = (__half*)alloc((size_t)128 * 64 * 2);
    float*  lsld    = (float*)alloc((size_t)NN * 4 * 4);
    int*    deg     = (int*)alloc((size_t)NN * 4);
    int*    row_ptr = (int*)alloc((size_t)(NN + 1) * 4);
    int*    cursor  = (int*)alloc((size_t)NN * 4);
    int*    bsum    = (int*)alloc(1024);
    int4*   csr     = (int4*)alloc((size_t)EE * 16);
    float*  wd      = (float*)alloc(256);
    float*  obuf    = (float*)alloc((size_t)GG * 256 * 4);

    const int NB = (NN + 255) / 256;  // 157

    // CSR by dst
    hipMemsetAsync(deg, 0, (size_t)NN * 4, stream);
    k_hist<<<(EE + 255) / 256, 256, 0, stream>>>(ei + EE, deg);
    k_scanA<<<NB, 256, 0, stream>>>(deg, row_ptr + 1, bsum);
    k_scanB<<<1, 256, 0, stream>>>(bsum, NB);
    k_scanC2<<<NB, 256, 0, stream>>>(row_ptr, bsum, deg, cursor);
    k_scatter<<<(EE + 255) / 256, 256, 0, stream>>>(ei, ea, mu, devp, cursor, csr);
    k_wedot<<<1, 64, 0, stream>>>(We, att_e, wd);
    k_prep<<<(XS + WGSZ + WESZ + 255) / 256, 256, 0, stream>>>(x, Wg, W_emb, x16, Wt, Wet);

    // embed (MFMA)
    k_embed16<<<NN / 16, 128, 0, stream>>>(x16, Wet, h0, h16a);

    float*  hc = h0;     float*  hn = h1;
    __half* hc16 = h16a; __half* hn16 = h16b;
    for (int k = 0; k < 3; ++k) {
        k_gemm16<<<NN / 16, 256, 0, stream>>>(hc16, Wt + (size_t)k * 32768,
                                              att_s + k * 256, att_d + k * 256, hh16, lsld);
        k_attn<<<NN / 8, 256, 0, stream>>>(hh16, hc, lsld, row_ptr, csr,
                                           wd + k * 2, bg + k * 128, gw + k * 256, gb + k,
                                           hn, hn16);
        float* t1 = hc; hc = hn; hn = t1;
        __half* t2 = hc16; hc16 = hn16; hn16 = t2;
    }

    k_readout<<<GG, 128, 0, stream>>>(hc, valid, batch, obuf);
    k_mlp<<<GG, 128, 0, stream>>>(obuf, fw0, fb0, fw1, fb1, fw2, fb2, fw3, fb3, out);
}

// Round 8
// 405.105 us; speedup vs baseline: 1.5701x; 1.0946x over previous
//
#include <hip/hip_runtime.h>
#include <hip/hip_fp16.h>
#include <math.h>

#define NN 40000
#define EE 500000
#define CC 128
#define GG 800
#define FINN 56
#define NEGS 0.2f
#define CAP 48

typedef _Float16 f16x8 __attribute__((ext_vector_type(8)));
typedef float f32x4 __attribute__((ext_vector_type(4)));

__device__ __forceinline__ float lrelu(float x) { return x > 0.f ? x : NEGS * x; }

// ---------------- prep: zero deg, Wt/Wet fp16 transposes, wedot ----------------
#define WGSZ (3 * 256 * 128)
#define WESZ (128 * 64)
#define PREPN ((WGSZ + WESZ) / 256)   // 416 full blocks; block 416 = wedot

__global__ void k_prep(const float* __restrict__ Wg, const float* __restrict__ W_emb,
                       const float* __restrict__ We, const float* __restrict__ ate,
                       __half* __restrict__ Wt, __half* __restrict__ Wet,
                       float* __restrict__ wd, int* __restrict__ deg) {
    int gi = blockIdx.x * 256 + threadIdx.x;
    if (gi < NN) deg[gi] = 0;
    if (blockIdx.x == PREPN) {
        if (threadIdx.x < 64) {
            int lane = threadIdx.x;
            for (int idx = 0; idx < 6; ++idx) {
                const float* w = We + idx * 128;
                const float* a = ate + idx * 128;
                float p = w[lane] * a[lane] + w[lane + 64] * a[lane + 64];
                #pragma unroll
                for (int m = 32; m; m >>= 1) p += __shfl_xor(p, m);
                if (lane == 0) wd[idx] = p;
            }
        }
        return;
    }
    if (gi < WGSZ) {                      // Wt[l][c][k] = Wg[l][k][c]
        int l = gi >> 15, rem = gi & 32767;
        int c = rem >> 7, kk = rem & 127;
        Wt[gi] = __float2half_rn(Wg[l * 32768 + kk * 256 + c]);
    } else {                              // Wet[c][k] = W_emb[k][c], K padded to 64
        int j = gi - WGSZ;
        int c = j >> 6, kk = j & 63;
        Wet[j] = (kk < FINN) ? __float2half_rn(W_emb[kk * CC + c]) : __half(0.f);
    }
}

// ---------------- slab CSR scatter: csr[d*CAP + slot] ----------------
__global__ void k_scatter(const int* __restrict__ ei, const float* __restrict__ ea,
                          const float* __restrict__ mu, const float* __restrict__ dev,
                          int* __restrict__ deg, int4* __restrict__ slab) {
    int e = blockIdx.x * 256 + threadIdx.x;
    if (e >= EE) return;
    int s = ei[e], d = ei[EE + e];
    float a1 = ea[2 * e];
    float xx = ea[2 * e + 1] - mu[0];
    float a2 = __expf(-xx * xx / dev[0]) + a1;
    int p = atomicAdd(&deg[d], 1);
    if (p < CAP) slab[d * CAP + p] = make_int4(s, __float_as_int(a1), __float_as_int(a2), 0);
}

// ---------------- embed via MFMA: h = x @ Wet^T (K=64), direct fp32 x ----------------
__global__ __launch_bounds__(128) void k_embed16(
    const float* __restrict__ x, const __half* __restrict__ Wet,
    float* __restrict__ h, __half* __restrict__ h16) {
    int tid = threadIdx.x;
    int wave = tid >> 6, lane = tid & 63;
    int row0 = blockIdx.x * 16;
    int rlo = lane & 15, kgrp = lane >> 4;
    const float* xrow = x + (row0 + rlo) * FINN;
    f16x8 a0, a1;
    #pragma unroll
    for (int j = 0; j < 8; ++j) a0[j] = (_Float16)xrow[kgrp * 8 + j];          // k in [0,32)
    #pragma unroll
    for (int j = 0; j < 8; ++j) {
        int k = 32 + kgrp * 8 + j;
        a1[j] = (k < FINN) ? (_Float16)xrow[k] : (_Float16)0.f;
    }
    #pragma unroll
    for (int nt = 0; nt < 4; ++nt) {
        int col = wave * 64 + nt * 16 + rlo;
        f32x4 acc = {0.f, 0.f, 0.f, 0.f};
        const __half* bbase = Wet + col * 64 + kgrp * 8;
        acc = __builtin_amdgcn_mfma_f32_16x16x32_f16(a0, *(const f16x8*)(bbase), acc, 0, 0, 0);
        acc = __builtin_amdgcn_mfma_f32_16x16x32_f16(a1, *(const f16x8*)(bbase + 32), acc, 0, 0, 0);
        #pragma unroll
        for (int r = 0; r < 4; ++r) {
            int row = row0 + kgrp * 4 + r;
            h[row * CC + col] = acc[r];
            h16[row * CC + col] = __float2half_rn(acc[r]);
        }
    }
}

// ---------------- MFMA GEMM: hh16 = h16 @ Wt^T, fused ls/ld ----------------
__global__ __launch_bounds__(256) void k_gemm16(
    const __half* __restrict__ h16, const __half* __restrict__ Wt,
    const float* __restrict__ as_, const float* __restrict__ ad_,
    __half* __restrict__ hh16, float* __restrict__ lsld) {
    __shared__ float2 red[16][4];
    int tid = threadIdx.x;
    int wave = tid >> 6, lane = tid & 63;
    int row0 = blockIdx.x * 16;
    int rlo = lane & 15, kgrp = lane >> 4;
    f16x8 afrag[4];
    const __half* abase = h16 + (row0 + rlo) * CC + kgrp * 8;
    #pragma unroll
    for (int ks = 0; ks < 4; ++ks) afrag[ks] = *(const f16x8*)(abase + ks * 32);
    int head = wave >> 1;
    const float* as_h = as_ + head * CC;
    const float* ad_h = ad_ + head * CC;
    float psum[4] = {0.f, 0.f, 0.f, 0.f}, pdsum[4] = {0.f, 0.f, 0.f, 0.f};
    #pragma unroll
    for (int nt = 0; nt < 4; ++nt) {
        int col = wave * 64 + nt * 16 + rlo;
        f32x4 acc = {0.f, 0.f, 0.f, 0.f};
        const __half* bbase = Wt + col * CC + kgrp * 8;
        #pragma unroll
        for (int ks = 0; ks < 4; ++ks) {
            f16x8 bfrag = *(const f16x8*)(bbase + ks * 32);
            acc = __builtin_amdgcn_mfma_f32_16x16x32_f16(afrag[ks], bfrag, acc, 0, 0, 0);
        }
        float av = as_h[col & 127], dv = ad_h[col & 127];
        #pragma unroll
        for (int r = 0; r < 4; ++r) {
            float v = acc[r];
            hh16[(row0 + kgrp * 4 + r) * 256 + col] = __float2half_rn(v);
            psum[r] += v * av;
            pdsum[r] += v * dv;
        }
    }
    #pragma unroll
    for (int r = 0; r < 4; ++r) {
        #pragma unroll
        for (int m = 1; m < 16; m <<= 1) {
            psum[r] += __shfl_xor(psum[r], m);
            pdsum[r] += __shfl_xor(pdsum[r], m);
        }
    }
    if (rlo == 0) {
        #pragma unroll
        for (int r = 0; r < 4; ++r) red[kgrp * 4 + r][wave] = make_float2(psum[r], pdsum[r]);
    }
    __syncthreads();
    if (tid < 64) {
        int row = tid >> 2, which = tid & 3;
        float v;
        if (which == 0)      v = red[row][0].x + red[row][1].x;  // ls0
        else if (which == 1) v = red[row][2].x + red[row][3].x;  // ls1
        else if (which == 2) v = red[row][0].y + red[row][1].y;  // ld0
        else                 v = red[row][2].y + red[row][3].y;  // ld1
        lsld[(row0 + row) * 4 + which] = v;
    }
}

// ---------------- fused attention: one node per half-wave, 4-edge-wide PV ----------------
__global__ __launch_bounds__(256) void k_attn(
    const __half* __restrict__ hh16, const float* __restrict__ hcur,
    const float* __restrict__ lsld,
    const int* __restrict__ deg, const int4* __restrict__ slab,
    const float* __restrict__ wd, const float* __restrict__ bg,
    const float* __restrict__ gw, const float* __restrict__ gb,
    float* __restrict__ hout, __half* __restrict__ h16out) {
    __shared__ float4 evM[8][32];
    __shared__ int    evS[8][32];
    int tid = threadIdx.x;
    int sub = tid & 31;
    int hw = tid >> 5;
    int n = blockIdx.x * 8 + hw;      // NN % 8 == 0
    float wd0 = wd[0], wd1 = wd[1];
    float4 nld = *(const float4*)&lsld[n * 4];
    float ld0 = nld.z, ld1 = nld.w;
    int count = min(deg[n], CAP);
    const int4* srow = slab + n * CAP;
    int hd01 = sub >> 4;
    float s0 = 0, s1 = 0, s2 = 0, s3 = 0;
    float acc1[8] = {0,0,0,0,0,0,0,0}, acc2[8] = {0,0,0,0,0,0,0,0};
    const char* hbase = (const char*)hh16 + sub * 16;

    for (int j0 = 0; j0 < count; j0 += 32) {
        int nact = min(32, count - j0);
        float4 e4 = make_float4(0.f, 0.f, 0.f, 0.f);
        int smine = 0;
        if (j0 + sub < count) {
            int4 c = srow[j0 + sub];
            smine = c.x;
            float a1 = __int_as_float(c.y), a2 = __int_as_float(c.z);
            float2 lsv = *(const float2*)&lsld[smine * 4];
            float b0 = lsv.x + ld0, b1 = lsv.y + ld1;
            e4.x = __expf(fminf(lrelu(b0 + a1 * wd0), 80.f));
            e4.y = __expf(fminf(lrelu(b0 + a2 * wd0), 80.f));
            e4.z = __expf(fminf(lrelu(b1 + a1 * wd1), 80.f));
            e4.w = __expf(fminf(lrelu(b1 + a2 * wd1), 80.f));
            s0 += e4.x; s1 += e4.y; s2 += e4.z; s3 += e4.w;
        }
        evM[hw][sub] = e4;                 // zero-padded beyond nact -> 4-wide loop needs no guards
        evS[hw][sub] = smine * 512;
        int npv = (nact + 3) & ~3;
        for (int jj = 0; jj < npv; jj += 4) {
            float4 emA = evM[hw][jj],     emB = evM[hw][jj + 1];
            float4 emC = evM[hw][jj + 2], emD = evM[hw][jj + 3];
            int oA = evS[hw][jj],     oB = evS[hw][jj + 1];
            int oC = evS[hw][jj + 2], oD = evS[hw][jj + 3];
            union { uint4 u; _Float16 hx[8]; } rA, rB, rC, rD;
            rA.u = *(const uint4*)(hbase + oA);
            rB.u = *(const uint4*)(hbase + oB);
            rC.u = *(const uint4*)(hbase + oC);
            rD.u = *(const uint4*)(hbase + oD);
            float eA1 = hd01 ? emA.z : emA.x, eA2 = hd01 ? emA.w : emA.y;
            float eB1 = hd01 ? emB.z : emB.x, eB2 = hd01 ? emB.w : emB.y;
            float eC1 = hd01 ? emC.z : emC.x, eC2 = hd01 ? emC.w : emC.y;
            float eD1 = hd01 ? emD.z : emD.x, eD2 = hd01 ? emD.w : emD.y;
            #pragma unroll
            for (int i = 0; i < 8; ++i) {
                float vA = (float)rA.hx[i], vB = (float)rB.hx[i];
                float vC = (float)rC.hx[i], vD = (float)rD.hx[i];
                acc1[i] += eA1 * vA; acc2[i] += eA2 * vA;
                acc1[i] += eB1 * vB; acc2[i] += eB2 * vB;
                acc1[i] += eC1 * vC; acc2[i] += eC2 * vC;
                acc1[i] += eD1 * vD; acc2[i] += eD2 * vD;
            }
        }
    }
    #pragma unroll
    for (int m = 16; m; m >>= 1) {
        s0 += __shfl_xor(s0, m); s1 += __shfl_xor(s1, m);
        s2 += __shfl_xor(s2, m); s3 += __shfl_xor(s3, m);
    }
    float d1 = (hd01 ? s2 : s0) + 1e-16f;
    float d2 = (hd01 ? s3 : s1) + 1e-16f;
    float id1 = 1.f / d1, id2 = 1.f / d2;
    int c0 = (sub & 15) * 8;
    float o1[8], o2[8];
    #pragma unroll
    for (int i = 0; i < 8; ++i) { o1[i] = acc1[i] * id1; o2[i] = acc2[i] * id2; }
    #pragma unroll
    for (int i = 0; i < 8; ++i) {
        o1[i] = 0.5f * (o1[i] + __shfl_xor(o1[i], 16)) + bg[c0 + i];
        o2[i] = 0.5f * (o2[i] + __shfl_xor(o2[i], 16)) + bg[c0 + i];
    }
    float hv[8];
    *(float4*)&hv[0] = ((const float4*)hcur)[n * 32 + (sub & 15) * 2];
    *(float4*)&hv[4] = ((const float4*)hcur)[n * 32 + (sub & 15) * 2 + 1];
    float pp1 = 0.f, pp2 = 0.f;
    if (sub < 16) {
        #pragma unroll
        for (int i = 0; i < 8; ++i) {
            pp1 += o1[i] * gw[128 + c0 + i];
            pp2 += o2[i] * gw[128 + c0 + i];
        }
    } else {
        float hp = 0.f;
        #pragma unroll
        for (int i = 0; i < 8; ++i) hp += hv[i] * gw[c0 + i];
        pp1 = hp; pp2 = hp;
    }
    #pragma unroll
    for (int m = 16; m; m >>= 1) { pp1 += __shfl_xor(pp1, m); pp2 += __shfl_xor(pp2, m); }
    float z1 = 1.f / (1.f + __expf(-(pp1 + gb[0])));
    float z2 = 1.f / (1.f + __expf(-(pp2 + gb[0])));
    if (sub < 16) {
        float r[8];
        #pragma unroll
        for (int i = 0; i < 8; ++i) {
            float g1 = z1 * hv[i] + (1.f - z1) * fmaxf(o1[i], 0.f);
            float g2 = z2 * hv[i] + (1.f - z2) * fmaxf(o2[i], 0.f);
            r[i] = g2 - g1;
        }
        ((float4*)hout)[n * 32 + (sub & 15) * 2]     = make_float4(r[0], r[1], r[2], r[3]);
        ((float4*)hout)[n * 32 + (sub & 15) * 2 + 1] = make_float4(r[4], r[5], r[6], r[7]);
        union { __half h[8]; uint4 u; } pk;
        #pragma unroll
        for (int i = 0; i < 8; ++i) pk.h[i] = __float2half_rn(r[i]);
        *(uint4*)&h16out[n * CC + c0] = pk.u;
    }
}

// ---------------- fused readout + MLP ----------------
__global__ __launch_bounds__(128) void k_readmlp(
    const float* __restrict__ h, const float* __restrict__ valid, const int* __restrict__ batch,
    const float* __restrict__ w0, const float* __restrict__ b0,
    const float* __restrict__ w1, const float* __restrict__ b1,
    const float* __restrict__ w2, const float* __restrict__ b2,
    const float* __restrict__ w3, const float* __restrict__ b3,
    float* __restrict__ out) {
    __shared__ float cur[256];
    __shared__ float nxt[128];
    int g = blockIdx.x, t = threadIdx.x;
    int lo = 0, hi = NN;
    while (lo < hi) { int mid = (lo + hi) >> 1; if (batch[mid] < g) lo = mid + 1; else hi = mid; }
    int s = lo;
    lo = s; hi = NN;
    while (lo < hi) { int mid = (lo + hi) >> 1; if (batch[mid] < g + 1) lo = mid + 1; else hi = mid; }
    int e = lo;
    float gl = 0, gp = 0;
    for (int n = s; n < e; ++n) {
        float hv = h[n * CC + t];
        gl += hv * valid[2 * n];
        gp += hv * valid[2 * n + 1];
    }
    cur[t] = gl; cur[t + 128] = gp;
    __syncthreads();
    float ss = b0[t];
    for (int i = 0; i < 256; ++i) ss += cur[i] * w0[i * 128 + t];
    nxt[t] = fmaxf(ss, 0.f);
    __syncthreads();
    ss = b1[t];
    for (int i = 0; i < 128; ++i) ss += nxt[i] * w1[i * 128 + t];
    cur[t] = fmaxf(ss, 0.f);
    __syncthreads();
    ss = b2[t];
    for (int i = 0; i < 128; ++i) ss += cur[i] * w2[i * 128 + t];
    nxt[t] = fmaxf(ss, 0.f);
    __syncthreads();
    if (t < 2) {
        float o = b3[t];
        for (int i = 0; i < 128; ++i) o += nxt[i] * w3[i * 2 + t];
        out[g * 2 + t] = (t == 1) ? expf(o) : o;
    }
}

extern "C" void kernel_launch(void* const* d_in, const int* in_sizes, int n_in,
                              void* d_out, int out_size, void* d_ws, size_t ws_size,
                              hipStream_t stream) {
    const float* x      = (const float*)d_in[0];
    const int*   ei     = (const int*)d_in[1];
    const float* ea     = (const float*)d_in[2];
    const float* valid  = (const float*)d_in[3];
    const int*   batch  = (const int*)d_in[4];
    const float* mu     = (const float*)d_in[5];
    const float* devp   = (const float*)d_in[6];
    const float* W_emb  = (const float*)d_in[7];
    const float* Wg     = (const float*)d_in[8];
    const float* att_s  = (const float*)d_in[9];
    const float* att_d  = (const float*)d_in[10];
    const float* We     = (const float*)d_in[11];
    const float* att_e  = (const float*)d_in[12];
    const float* bg     = (const float*)d_in[13];
    const float* gw     = (const float*)d_in[14];
    const float* gb     = (const float*)d_in[15];
    const float* fw0    = (const float*)d_in[16];
    const float* fb0    = (const float*)d_in[17];
    const float* fw1    = (const float*)d_in[18];
    const float* fb1    = (const float*)d_in[19];
    const float* fw2    = (const float*)d_in[20];
    const float* fb2    = (const float*)d_in[21];
    const float* fw3    = (const float*)d_in[22];
    const float* fb3    = (const float*)d_in[23];
    float* out = (float*)d_out;

    char* p = (char*)d_ws;
    auto alloc = [&](size_t bytes) -> char* {
        char* r = p;
        p += (bytes + 255) & ~(size_t)255;
        return r;
    };
    float*  h0      = (float*)alloc((size_t)NN * CC * 4);
    float*  h1      = (float*)alloc((size_t)NN * CC * 4);
    __half* h16a    = (__half*)alloc((size_t)NN * CC * 2);
    __half* h16b    = (__half*)alloc((size_t)NN * CC * 2);
    __half* hh16    = (__half*)alloc((size_t)NN * 256 * 2);
    __half* Wt      = (__half*)alloc((size_t)3 * 256 * 128 * 2);
    __half* Wet     = (__half*)alloc((size_t)128 * 64 * 2);
    float*  lsld    = (float*)alloc((size_t)NN * 4 * 4);
    int*    deg     = (int*)alloc((size_t)NN * 4);
    int4*   slab    = (int4*)alloc((size_t)NN * CAP * 16);
    float*  wd      = (float*)alloc(256);

    // 1: prep (zeros deg, Wt/Wet, wedot)
    k_prep<<<PREPN + 1, 256, 0, stream>>>(Wg, W_emb, We, att_e, Wt, Wet, wd, deg);
    // 2: slab CSR scatter
    k_scatter<<<(EE + 255) / 256, 256, 0, stream>>>(ei, ea, mu, devp, deg, slab);
    // 3: embed (MFMA, direct fp32 x)
    k_embed16<<<NN / 16, 128, 0, stream>>>(x, Wet, h0, h16a);

    float*  hc = h0;     float*  hn = h1;
    __half* hc16 = h16a; __half* hn16 = h16b;
    for (int k = 0; k < 3; ++k) {
        k_gemm16<<<NN / 16, 256, 0, stream>>>(hc16, Wt + (size_t)k * 32768,
                                              att_s + k * 256, att_d + k * 256, hh16, lsld);
        k_attn<<<NN / 8, 256, 0, stream>>>(hh16, hc, lsld, deg, slab,
                                           wd + k * 2, bg + k * 128, gw + k * 256, gb + k,
                                           hn, hn16);
        float* t1 = hc; hc = hn; hn = t1;
        __half* t2 = hc16; hc16 = hn16; hn16 = t2;
    }

    // 10: fused readout + MLP
    k_readmlp<<<GG, 128, 0, stream>>>(hc, valid, batch,
                                      fw0, fb0, fw1, fb1, fw2, fb2, fw3, fb3, out);
}